// Round 1
// baseline (922.242 us; speedup 1.0000x reference)
//
#include <hip/hip_runtime.h>
#include <hip/hip_bf16.h>

// B=64, C=32, V=1024, L=12, C_OUT=64, C_CAT=224
// M = B*C*L = 24576 rows; N = 6 slices * 1024 = 6144 cols; K = 1024.
// Slice order s: 0=A0^T, 1=(A0^2)^T, 2=A1^T, 3=(A1^2)^T, 4=A2^T, 5=(A2^2)^T

typedef __attribute__((ext_vector_type(4))) float  f32x4;
typedef __attribute__((ext_vector_type(8))) short  s16x8;
typedef __attribute__((ext_vector_type(4))) short  s16x4;

__device__ inline short f2bf(float f) {
    unsigned u = __builtin_bit_cast(unsigned, f);
    unsigned r = (u + 0x7FFFu + ((u >> 16) & 1u)) >> 16;   // RNE
    return (short)r;
}

__device__ inline f32x4 mfma16(s16x8 a, s16x8 b, f32x4 c) {
    return __builtin_amdgcn_mfma_f32_16x16x32_bf16(a, b, c, 0, 0, 0);
}

__device__ inline void gll16(const void* g, void* l) {
    __builtin_amdgcn_global_load_lds(
        (const __attribute__((address_space(1))) void*)g,
        (__attribute__((address_space(3))) void*)l, 16, 0, 0);
}

// ---------------------------------------------------------------------------
// x [B,C,V,L] fp32 -> Xg bf16 [(bc)*12 + l][v].  One block per bc slab.
__global__ __launch_bounds__(256) void cast_x_v2(const float* __restrict__ x,
                                                 short* __restrict__ Xg) {
    __shared__ short Xl[12 * 1040];
    const int bc = blockIdx.x;
    const int t  = threadIdx.x;
    const float4* src = (const float4*)(x + (size_t)bc * 12288);
#pragma unroll
    for (int k = 0; k < 12; ++k) {
        int f4 = k * 256 + t;                 // 0..3071
        float4 v = src[f4];
        int f  = f4 * 4;
        int vi = f / 12;
        int li = f - vi * 12;
        float vals[4] = {v.x, v.y, v.z, v.w};
#pragma unroll
        for (int e = 0; e < 4; ++e) {
            Xl[li * 1040 + vi] = f2bf(vals[e]);
            if (++li == 12) { li = 0; ++vi; }
        }
    }
    __syncthreads();
#pragma unroll
    for (int k = 0; k < 6; ++k) {
        int ch = k * 256 + t;                 // 0..1535
        int l  = ch >> 7;
        int v8 = ch & 127;
        *(s16x8*)(Xg + ((size_t)bc * 12 + l) * 1024 + v8 * 8) =
            *(const s16x8*)&Xl[l * 1040 + v8 * 8];
    }
}

// ---------------------------------------------------------------------------
// A_j [v][w] fp32 -> At_j bf16 [w][v] (into Bt_all slice 2j)  +  Ab_j bf16 [v][w]
__global__ __launch_bounds__(256) void cast_a_v2(const float* __restrict__ a0,
                                                 const float* __restrict__ a1,
                                                 const float* __restrict__ a2,
                                                 short* __restrict__ Btall,
                                                 short* __restrict__ Ab) {
    __shared__ float tbuf[32][33];
    const int z = blockIdx.z;
    const float* A = (z == 0) ? a0 : ((z == 1) ? a1 : a2);
    const int v0 = blockIdx.x * 32;
    const int w0 = blockIdx.y * 32;
    const int tr = threadIdx.x >> 3;
    const int tc = (threadIdx.x & 7) << 2;
    float4 val = *(const float4*)&A[(size_t)(v0 + tr) * 1024 + w0 + tc];
    s16x4 sb;
    sb[0] = f2bf(val.x); sb[1] = f2bf(val.y); sb[2] = f2bf(val.z); sb[3] = f2bf(val.w);
    *(s16x4*)(Ab + (size_t)z * 1048576 + (size_t)(v0 + tr) * 1024 + w0 + tc) = sb;
    tbuf[tr][tc + 0] = val.x; tbuf[tr][tc + 1] = val.y;
    tbuf[tr][tc + 2] = val.z; tbuf[tr][tc + 3] = val.w;
    __syncthreads();
    s16x4 st;
#pragma unroll
    for (int i = 0; i < 4; ++i) st[i] = f2bf(tbuf[tc + i][tr]);
    *(s16x4*)(Btall + (size_t)(2 * z) * 1048576 + (size_t)(w0 + tr) * 1024 + v0 + tc) = st;
}

// ---------------------------------------------------------------------------
// Small BT-GEMM (kept for the A^2 step): 128x128 tile, BK=32, m97 structure.
__global__ __launch_bounds__(256, 2) void gemm_bt(const short* __restrict__ Xb, long xz,
                                                  const short* __restrict__ Btb, long bz,
                                                  short* __restrict__ Cb, long cz,
                                                  int crow) {
    __shared__ __align__(16) short Alds[128 * 32];
    __shared__ __align__(16) short Blds[128 * 32];

    const int tid  = threadIdx.x;
    const int lane = tid & 63;
    const int wid  = tid >> 6;
    const int wm   = wid >> 1;
    const int wn   = wid & 1;
    const int m0   = blockIdx.y * 128;
    const int n0   = blockIdx.x * 128;

    const short* X  = Xb  + (size_t)blockIdx.z * xz;
    const short* Bt = Btb + (size_t)blockIdx.z * bz;
    short*       C  = Cb  + (size_t)blockIdx.z * cz;

    const short* Ag = X  + (size_t)(m0 + wid * 32 + (lane >> 2)) * 1024 + (lane & 3) * 8;
    const short* Bg = Bt + (size_t)(n0 + wid * 32 + (lane >> 2)) * 1024 + (lane & 3) * 8;
    short* la = &Alds[wid * 1024];
    short* lb = &Blds[wid * 1024];

    const int lane15 = lane & 15;
    const int lq     = lane >> 4;
    const int ar     = lane15 * 32 + lq * 8;

    f32x4 acc[4][4] = {};

    for (int k0 = 0; k0 < 1024; k0 += 32) {
        __syncthreads();
        gll16(Ag + k0, la);
        gll16(Ag + k0 + 16 * 1024, la + 512);
        gll16(Bg + k0, lb);
        gll16(Bg + k0 + 16 * 1024, lb + 512);
        __syncthreads();

        s16x8 af[4], bf[4];
#pragma unroll
        for (int i = 0; i < 4; ++i)
            af[i] = *(const s16x8*)&Alds[(wm * 64 + i * 16) * 32 + ar];
#pragma unroll
        for (int j = 0; j < 4; ++j)
            bf[j] = *(const s16x8*)&Blds[(wn * 64 + j * 16) * 32 + ar];
#pragma unroll
        for (int i = 0; i < 4; ++i)
#pragma unroll
            for (int j = 0; j < 4; ++j)
                acc[i][j] = mfma16(af[i], bf[j], acc[i][j]);
    }

#pragma unroll
    for (int i = 0; i < 4; ++i) {
        int rbase = m0 + wm * 64 + i * 16 + lq * 4;
#pragma unroll
        for (int r = 0; r < 4; ++r) {
            size_t rowoff = (size_t)(rbase + r) * crow;
#pragma unroll
            for (int j = 0; j < 4; ++j) {
                int col = n0 + wn * 64 + j * 16 + lane15;
                C[rowoff + col] = f2bf(acc[i][j][r]);
            }
        }
    }
}

// ---------------------------------------------------------------------------
// Main GEMM: 256x256 tile, BK=64, 8 waves (2Mx4N), 512 threads, 128 KiB LDS,
// 8-phase schedule with counted vmcnt (T2+T3+T4+T5 from the 8-phase template).
//
// LDS layout per operand: [dbuf(2)][half(2)] blocks of 8192 bf16 (16 KiB).
//   A-half h = tile rows r with ((r>>6)&1)==h  (per-wave M-half: wave wm reads
//     local rows wm*64+[0,64) of half Mh).
//   B-half h = tile rows n with ((n>>5)&1)==h  (per-wave N-half, wn*32+[0,32)).
//   Inside a half-tile [128 local rows][64 k]: contiguous 16x32 subtiles
//     (subtile = (rl>>4)*2 + kblk, inner = (rl&15)*32 + kk*8 shorts) ->
//     frag reads hit banks (r&1)*16+q*4 : all 32 banks, conflict-free.
// Stage (global_load_lds, linear dest): thread t, load i covers granule
//   gd=i*512+t -> local row rl=(gd>>4... ) matching the subtiled layout; the
//   global SOURCE address is permuted to match (both-sides-or-neither).
//
// Per tile τ (4 phases, quadrant = (MH,NH)):
//   p1 (M0,N0): stage A-h1(τ+1);  p2 (M0,N1): stage B-h1(τ+1)
//   p3 (M1,N0): stage A-h0(τ+2);  p4 (M1,N1): stage B-h0(τ+2) + vmcnt(4)
// Liveness: each region's last read is ≥1 s_barrier before its re-stage.
// vmcnt(4) at p4 allows exactly the p3/p4 stages in flight; everything the
// next 4 phases read is older -> landed.

#define SB0  __builtin_amdgcn_sched_barrier(0)
#define BARM asm volatile("s_barrier" ::: "memory")

#define STAGE_A(d, h, kt) do {                                               \
    const short* _s = X + (size_t)(m0 + rA + (h) * 64) * 1024 + (kt) * 64 + kin; \
    short* _l = Als + ((((d) * 2 + (h)) << 13) + wds);                       \
    gll16(_s, _l);                                                           \
    gll16(_s + 128 * 1024, _l + 4096);                                       \
} while (0)

#define STAGE_B(d, h, kt) do {                                               \
    const short* _s = Bt + (size_t)(n0 + rB + (h) * 32) * 1024 + (kt) * 64 + kin; \
    short* _l = Bls + ((((d) * 2 + (h)) << 13) + wds);                       \
    gll16(_s, _l);                                                           \
    gll16(_s + 128 * 1024, _l + 4096);                                       \
} while (0)

#define PHASE(D, MH, NH, SSTMT, VMSTMT) do {                                 \
    s16x8 _af[4][2], _bv[2][2];                                              \
    const short* _ab = Als + ((((D) * 2 + (MH)) << 13) + r15 * 32 + q * 8);  \
    const short* _bb = Bls + ((((D) * 2 + (NH)) << 13) + r15 * 32 + q * 8);  \
    _Pragma("unroll")                                                        \
    for (int _fm = 0; _fm < 4; ++_fm) {                                      \
        _Pragma("unroll")                                                    \
        for (int _kk = 0; _kk < 2; ++_kk)                                    \
            _af[_fm][_kk] = *(const s16x8*)(_ab + (((wm * 4 + _fm) * 2 + _kk) << 9)); \
    }                                                                        \
    _Pragma("unroll")                                                        \
    for (int _fn = 0; _fn < 2; ++_fn) {                                      \
        _Pragma("unroll")                                                    \
        for (int _kk = 0; _kk < 2; ++_kk)                                    \
            _bv[_fn][_kk] = *(const s16x8*)(_bb + (((wn * 2 + _fn) * 2 + _kk) << 9)); \
    }                                                                        \
    SSTMT                                                                    \
    SB0; BARM; SB0;                                                          \
    asm volatile("s_waitcnt lgkmcnt(0)" ::: "memory");                       \
    SB0;                                                                     \
    __builtin_amdgcn_s_setprio(1);                                           \
    _Pragma("unroll")                                                        \
    for (int _fm = 0; _fm < 4; ++_fm) {                                      \
        _Pragma("unroll")                                                    \
        for (int _fn = 0; _fn < 2; ++_fn) {                                  \
            _Pragma("unroll")                                                \
            for (int _kk = 0; _kk < 2; ++_kk)                                \
                acc[(MH) * 4 + _fm][(NH) * 2 + _fn] =                        \
                    mfma16(_af[_fm][_kk], _bv[_fn][_kk],                     \
                           acc[(MH) * 4 + _fm][(NH) * 2 + _fn]);             \
        }                                                                    \
    }                                                                        \
    __builtin_amdgcn_s_setprio(0);                                           \
    SB0;                                                                     \
    VMSTMT                                                                   \
    BARM; SB0;                                                               \
} while (0)

#define VM4 { asm volatile("s_waitcnt vmcnt(4)" ::: "memory"); }
#define VM0 { asm volatile("s_waitcnt vmcnt(0)" ::: "memory"); }
#define VMN { ; }
#define NOSTG { ; }

#define TILE(D, T, S1, S2, VMSTMT) do {                                      \
    PHASE(D, 0, 0, { if (S1) STAGE_A(1 - (D), 1, (T) + 1); }, VMN);          \
    PHASE(D, 0, 1, { if (S1) STAGE_B(1 - (D), 1, (T) + 1); }, VMN);          \
    PHASE(D, 1, 0, { if (S2) STAGE_A((D), 0, (T) + 2); },     VMN);          \
    PHASE(D, 1, 1, { if (S2) STAGE_B((D), 0, (T) + 2); },     VMSTMT);       \
} while (0)

__global__ __launch_bounds__(512, 2) void gemm256(const short* __restrict__ X,
                                                  const short* __restrict__ Bt,
                                                  short* __restrict__ C) {
    __shared__ __align__(16) short Als[32768];   // 64 KiB
    __shared__ __align__(16) short Bls[32768];   // 64 KiB

    const int t    = threadIdx.x;
    const int lane = t & 63;
    const int w    = t >> 6;          // wave 0..7
    const int wm   = w >> 2;          // 0..1
    const int wn   = w & 3;           // 0..3
    const int r15  = lane & 15;
    const int q    = lane >> 4;       // 0..3
    const int m0   = blockIdx.y << 8;
    const int n0   = blockIdx.x << 8;

    // staging per-thread geometry (load i=0; i=1 is +128 global rows, +4096 shorts)
    const int rl0 = ((t >> 7) << 4) | ((t >> 2) & 15);           // local row 0..63
    const int kin = (((t >> 6) & 1) << 5) | ((t & 3) << 3);      // k offset in tile
    const int rA  = rl0;                                         // A global row base
    const int rB  = ((rl0 >> 5) << 6) | (rl0 & 31);              // B global row base
    const int wds = w << 9;                                      // wave LDS base (shorts)

    f32x4 acc[8][4] = {};

    // prologue: T0 complete + T1 h0 halves; wait all of T0 (allow T1-h0 in flight)
    STAGE_A(0, 0, 0); STAGE_A(0, 1, 0); STAGE_B(0, 0, 0); STAGE_B(0, 1, 0);
    STAGE_A(1, 0, 1); STAGE_B(1, 0, 1);
    asm volatile("s_waitcnt vmcnt(4)" ::: "memory");
    BARM; SB0;

#pragma unroll 1
    for (int it = 0; it < 7; ++it) {
        const int T = it * 2;
        TILE(0, T,     true, true, VM4);
        TILE(1, T + 1, true, true, VM4);
    }
    TILE(0, 14, true,  false, VM0);   // stages h1(15) only; drain before last tile
    TILE(1, 15, false, false, VMN);   // pure compute

    // epilogue: D col = lane&15, row = q*4 + reg
#pragma unroll
    for (int fmt = 0; fmt < 8; ++fmt) {
        const int rbase = m0 + wm * 128 + fmt * 16 + q * 4;
#pragma unroll
        for (int r = 0; r < 4; ++r) {
            size_t rowoff = (size_t)(rbase + r) * 6144;
#pragma unroll
            for (int fnt = 0; fnt < 4; ++fnt) {
                int col = n0 + wn * 64 + fnt * 16 + r15;
                C[rowoff + col] = f2bf(acc[fmt][fnt][r]);
            }
        }
    }
}

// ---------------------------------------------------------------------------
// Final 1x1 conv (unchanged this round).
__global__ __launch_bounds__(256, 2) void final_gemm2(const float* __restrict__ x,
                                                      const short* __restrict__ H,
                                                      const float* __restrict__ W,
                                                      const float* __restrict__ bias,
                                                      float* __restrict__ out) {
    __shared__ __align__(16) short Wl[64 * 40];
    __shared__ __align__(16) short Hl[384 * 40];

    const int t  = threadIdx.x;
    const int lane = t & 63;
    const int wv   = t >> 6;
    const int lane15 = lane & 15;
    const int lq     = lane >> 4;
    const int n  = blockIdx.y;
    const int v0 = blockIdx.x * 32;
    const int p0 = v0 * 12;

    const int hc    = t & 31;
    const int hw    = t >> 5;        // 0..7
    const int l_lo  = hw & 1;
    const int lane4 = hw >> 1;       // 0..3  (constant per wave)

    f32x4 acc[4][6] = {};

    for (int g = 0; g < 7; ++g) {
        __syncthreads();
        {
            int o = t >> 2, c0 = (t & 3) * 8;
            const float* wp = W + (size_t)o * 224 + g * 32 + c0;
            float4 w0 = *(const float4*)wp;
            float4 w1 = *(const float4*)(wp + 4);
            short* d = &Wl[o * 40 + c0];
            d[0] = f2bf(w0.x); d[1] = f2bf(w0.y); d[2] = f2bf(w0.z); d[3] = f2bf(w0.w);
            d[4] = f2bf(w1.x); d[5] = f2bf(w1.y); d[6] = f2bf(w1.z); d[7] = f2bf(w1.w);
        }
        if (g == 0) {
            int c = t >> 3, j0 = t & 7;
            const float* src = x + ((size_t)n * 32 + c) * 12288 + p0;
#pragma unroll
            for (int it = 0; it < 12; ++it) {
                int ch = j0 + it * 8;          // 0..95
                float4 v = *(const float4*)(src + ch * 4);
                int p = ch * 4;
                Hl[(p + 0) * 40 + c] = f2bf(v.x);
                Hl[(p + 1) * 40 + c] = f2bf(v.y);
                Hl[(p + 2) * 40 + c] = f2bf(v.z);
                Hl[(p + 3) * 40 + c] = f2bf(v.w);
            }
        } else {
            const short* base = H + (size_t)(g - 1) * 1024 + v0 + lane4 * 8;
#pragma unroll
            for (int lt = 0; lt < 6; ++lt) {
                int l = l_lo + 2 * lt;
                size_t row = ((size_t)n * 32 + hc) * 12 + l;
                s16x8 h8 = *(const s16x8*)(base + row * 6144);
#pragma unroll
                for (int i = 0; i < 8; ++i)
                    Hl[((lane4 * 8 + i) * 12 + l) * 40 + hc] = h8[i];
            }
        }
        __syncthreads();

        s16x8 af[4], bf[6];
#pragma unroll
        for (int ot = 0; ot < 4; ++ot)
            af[ot] = *(const s16x8*)&Wl[(ot * 16 + lane15) * 40 + lq * 8];
#pragma unroll
        for (int bt = 0; bt < 6; ++bt)
            bf[bt] = *(const s16x8*)&Hl[(wv * 96 + bt * 16 + lane15) * 40 + lq * 8];
#pragma unroll
        for (int ot = 0; ot < 4; ++ot)
#pragma unroll
            for (int bt = 0; bt < 6; ++bt)
                acc[ot][bt] = mfma16(af[ot], bf[bt], acc[ot][bt]);
    }

#pragma unroll
    for (int ot = 0; ot < 4; ++ot) {
#pragma unroll
        for (int r = 0; r < 4; ++r) {
            int o = ot * 16 + lq * 4 + r;
            float bo = bias[o];
            float* op = out + ((size_t)n * 64 + o) * 12288 + p0;
#pragma unroll
            for (int bt = 0; bt < 6; ++bt) {
                int p = wv * 96 + bt * 16 + lane15;
                op[p] = acc[ot][bt][r] + bo;
            }
        }
    }
}

// ---------------------------------------------------------------------------
extern "C" void kernel_launch(void* const* d_in, const int* in_sizes, int n_in,
                              void* d_out, int out_size, void* d_ws, size_t ws_size,
                              hipStream_t stream) {
    const float* x  = (const float*)d_in[0];
    const float* a0 = (const float*)d_in[1];
    const float* a1 = (const float*)d_in[2];
    const float* a2 = (const float*)d_in[3];
    const float* W  = (const float*)d_in[4];
    const float* bs = (const float*)d_in[5];
    float* out = (float*)d_out;

    // workspace (bytes):
    //   Xg    bf16 [24576][1024]   @ 0           50,331,648
    //   Ab    bf16 [3][1024][1024] @ 50331648     6,291,456
    //   Btall bf16 [6][1024][1024] @ 56623104    12,582,912
    //   Hmv   bf16 [24576][6144]   @ 69206016   301,989,888   (ends 371,195,904)
    char* ws = (char*)d_ws;
    short* Xg    = (short*)(ws);
    short* Ab    = (short*)(ws + 50331648L);
    short* Btall = (short*)(ws + 56623104L);
    short* Hmv   = (short*)(ws + 69206016L);

    cast_x_v2<<<2048, 256, 0, stream>>>(x, Xg);
    cast_a_v2<<<dim3(32, 32, 3), 256, 0, stream>>>(a0, a1, a2, Btall, Ab);

    // (A_j^2)^T via small BT-GEMM -> slice 2j+1
    gemm_bt<<<dim3(8, 8, 3), 256, 0, stream>>>(
        Btall, 2097152L, Ab, 1048576L, Btall + 1048576L, 2097152L, 1024);

    // all 6 diffusion outputs in one 8-phase 256^2 GEMM: Hmv[m][s*1024+v]
    gemm256<<<dim3(24, 96), 512, 0, stream>>>(Xg, Btall, Hmv);

    final_gemm2<<<dim3(32, 64), 256, 0, stream>>>(x, Hmv, W, bs, out);
}

// Round 2
// 792.571 us; speedup vs baseline: 1.1636x; 1.1636x over previous
//
#include <hip/hip_runtime.h>
#include <hip/hip_bf16.h>

// B=64, C=32, V=1024, L=12, C_OUT=64, C_CAT=224
// M = B*C*L = 24576 rows; N = 6 slices * 1024 = 6144 cols; K = 1024.
// Slice order s: 0=A0^T, 1=(A0^2)^T, 2=A1^T, 3=(A1^2)^T, 4=A2^T, 5=(A2^2)^T

typedef __attribute__((ext_vector_type(4))) float  f32x4;
typedef __attribute__((ext_vector_type(8))) short  s16x8;
typedef __attribute__((ext_vector_type(4))) short  s16x4;

__device__ inline short f2bf(float f) {
    unsigned u = __builtin_bit_cast(unsigned, f);
    unsigned r = (u + 0x7FFFu + ((u >> 16) & 1u)) >> 16;   // RNE
    return (short)r;
}

__device__ inline f32x4 mfma16(s16x8 a, s16x8 b, f32x4 c) {
    return __builtin_amdgcn_mfma_f32_16x16x32_bf16(a, b, c, 0, 0, 0);
}

__device__ inline void gll16(const void* g, void* l) {
    __builtin_amdgcn_global_load_lds(
        (const __attribute__((address_space(1))) void*)g,
        (__attribute__((address_space(3))) void*)l, 16, 0, 0);
}

// ---------------------------------------------------------------------------
// x [B,C,V,L] fp32 -> Xg bf16 [(bc)*12 + l][v].  One block per bc slab.
__global__ __launch_bounds__(256) void cast_x_v2(const float* __restrict__ x,
                                                 short* __restrict__ Xg) {
    __shared__ short Xl[12 * 1040];
    const int bc = blockIdx.x;
    const int t  = threadIdx.x;
    const float4* src = (const float4*)(x + (size_t)bc * 12288);
#pragma unroll
    for (int k = 0; k < 12; ++k) {
        int f4 = k * 256 + t;                 // 0..3071
        float4 v = src[f4];
        int f  = f4 * 4;
        int vi = f / 12;
        int li = f - vi * 12;
        float vals[4] = {v.x, v.y, v.z, v.w};
#pragma unroll
        for (int e = 0; e < 4; ++e) {
            Xl[li * 1040 + vi] = f2bf(vals[e]);
            if (++li == 12) { li = 0; ++vi; }
        }
    }
    __syncthreads();
#pragma unroll
    for (int k = 0; k < 6; ++k) {
        int ch = k * 256 + t;                 // 0..1535
        int l  = ch >> 7;
        int v8 = ch & 127;
        *(s16x8*)(Xg + ((size_t)bc * 12 + l) * 1024 + v8 * 8) =
            *(const s16x8*)&Xl[l * 1040 + v8 * 8];
    }
}

// ---------------------------------------------------------------------------
// A_j [v][w] fp32 -> At_j bf16 [w][v] (into Bt_all slice 2j)  +  Ab_j bf16 [v][w]
__global__ __launch_bounds__(256) void cast_a_v2(const float* __restrict__ a0,
                                                 const float* __restrict__ a1,
                                                 const float* __restrict__ a2,
                                                 short* __restrict__ Btall,
                                                 short* __restrict__ Ab) {
    __shared__ float tbuf[32][33];
    const int z = blockIdx.z;
    const float* A = (z == 0) ? a0 : ((z == 1) ? a1 : a2);
    const int v0 = blockIdx.x * 32;
    const int w0 = blockIdx.y * 32;
    const int tr = threadIdx.x >> 3;
    const int tc = (threadIdx.x & 7) << 2;
    float4 val = *(const float4*)&A[(size_t)(v0 + tr) * 1024 + w0 + tc];
    s16x4 sb;
    sb[0] = f2bf(val.x); sb[1] = f2bf(val.y); sb[2] = f2bf(val.z); sb[3] = f2bf(val.w);
    *(s16x4*)(Ab + (size_t)z * 1048576 + (size_t)(v0 + tr) * 1024 + w0 + tc) = sb;
    tbuf[tr][tc + 0] = val.x; tbuf[tr][tc + 1] = val.y;
    tbuf[tr][tc + 2] = val.z; tbuf[tr][tc + 3] = val.w;
    __syncthreads();
    s16x4 st;
#pragma unroll
    for (int i = 0; i < 4; ++i) st[i] = f2bf(tbuf[tc + i][tr]);
    *(s16x4*)(Btall + (size_t)(2 * z) * 1048576 + (size_t)(w0 + tr) * 1024 + v0 + tc) = st;
}

// ---------------------------------------------------------------------------
// Small BT-GEMM (kept for the A^2 step): 128x128 tile, BK=32, m97 structure.
__global__ __launch_bounds__(256, 2) void gemm_bt(const short* __restrict__ Xb, long xz,
                                                  const short* __restrict__ Btb, long bz,
                                                  short* __restrict__ Cb, long cz,
                                                  int crow) {
    __shared__ __align__(16) short Alds[128 * 32];
    __shared__ __align__(16) short Blds[128 * 32];

    const int tid  = threadIdx.x;
    const int lane = tid & 63;
    const int wid  = tid >> 6;
    const int wm   = wid >> 1;
    const int wn   = wid & 1;
    const int m0   = blockIdx.y * 128;
    const int n0   = blockIdx.x * 128;

    const short* X  = Xb  + (size_t)blockIdx.z * xz;
    const short* Bt = Btb + (size_t)blockIdx.z * bz;
    short*       C  = Cb  + (size_t)blockIdx.z * cz;

    const short* Ag = X  + (size_t)(m0 + wid * 32 + (lane >> 2)) * 1024 + (lane & 3) * 8;
    const short* Bg = Bt + (size_t)(n0 + wid * 32 + (lane >> 2)) * 1024 + (lane & 3) * 8;
    short* la = &Alds[wid * 1024];
    short* lb = &Blds[wid * 1024];

    const int lane15 = lane & 15;
    const int lq     = lane >> 4;
    const int ar     = lane15 * 32 + lq * 8;

    f32x4 acc[4][4] = {};

    for (int k0 = 0; k0 < 1024; k0 += 32) {
        __syncthreads();
        gll16(Ag + k0, la);
        gll16(Ag + k0 + 16 * 1024, la + 512);
        gll16(Bg + k0, lb);
        gll16(Bg + k0 + 16 * 1024, lb + 512);
        __syncthreads();

        s16x8 af[4], bf[4];
#pragma unroll
        for (int i = 0; i < 4; ++i)
            af[i] = *(const s16x8*)&Alds[(wm * 64 + i * 16) * 32 + ar];
#pragma unroll
        for (int j = 0; j < 4; ++j)
            bf[j] = *(const s16x8*)&Blds[(wn * 64 + j * 16) * 32 + ar];
#pragma unroll
        for (int i = 0; i < 4; ++i)
#pragma unroll
            for (int j = 0; j < 4; ++j)
                acc[i][j] = mfma16(af[i], bf[j], acc[i][j]);
    }

#pragma unroll
    for (int i = 0; i < 4; ++i) {
        int rbase = m0 + wm * 64 + i * 16 + lq * 4;
#pragma unroll
        for (int r = 0; r < 4; ++r) {
            size_t rowoff = (size_t)(rbase + r) * crow;
#pragma unroll
            for (int j = 0; j < 4; ++j) {
                int col = n0 + wn * 64 + j * 16 + lane15;
                C[rowoff + col] = f2bf(acc[i][j][r]);
            }
        }
    }
}

// ---------------------------------------------------------------------------
// Main GEMM v2: 256x256 tile, BK=64, 8 waves (2Mx4N), 512 threads, 128 KiB LDS.
// 8-phase (2 K-tiles/iter) with counted vmcnt, SNAKE quadrant order
// (M0N0 -> M0N1 -> M1N1 -> M1N0) and B-fragments register-held across the
// tile: 24 ds_read_b128 per wave per K-tile (12/4/8/0 per phase).
//
// LDS: per operand [dbuf 2][half 2] blocks of 8192 shorts (16 KiB).
//   A-half h = tile rows with bit6==h (local row rl = ((row>>7)<<6)|(row&63));
//   B-half h = tile rows with bit5==h (rl = ((row>>6)<<5)|(row&31)).
// Half-tile = 1024 chunks of 16B (8 k-chunks x 128 rows), stored with per-row
// ROTATION: chunk(row,kc) lives at slot row*8 + ((kc+row)&7).  Any fragment
// read (lane(r15,q) wants (rowbase+r15, kc=kk*4+q)) then has every
// consecutive-8-lane group covering all 8 granules (all 32 banks) exactly
// once -> conflict-free under any serialization model.  Staging keeps the
// LDS dest linear (gll requirement) and pre-rotates the global SOURCE:
// thread t reads k-chunk kc=((t&7)-(t>>3))&7 of row (t>>3) — each 8-thread
// group still covers one full 128B segment (perfectly coalesced).
//
// Stage schedule per tile T (buffer D=T&1), unchanged from verified r1:
//   P1: stage A(1-D,h1,T+1)   P2: stage B(1-D,h1,T+1)
//   P3: stage A(D,h0,T+2)     P4: stage B(D,h0,T+2) + vmcnt(4)
// All LDS reads of a phase complete at that phase's lgkmcnt(0) (before its
// trailing barrier), so every re-stage is >=2 barriers after the last read.

#define SB0   __builtin_amdgcn_sched_barrier(0)
#define BARM  asm volatile("s_barrier" ::: "memory")
#define LGKM0 asm volatile("s_waitcnt lgkmcnt(0)" ::: "memory")

#define STAGE_A(d, h, kt) do {                                               \
    const short* _s = Agp + (h) * 65536 + (kt) * 64;                         \
    short* _l = lA + (((d) * 2 + (h)) << 13);                                \
    gll16(_s, _l);                                                           \
    gll16(_s + 131072, _l + 4096);                                           \
} while (0)

#define STAGE_B(d, h, kt) do {                                               \
    const short* _s = Bgp + (h) * 32768 + (kt) * 64;                         \
    short* _l = lB + (((d) * 2 + (h)) << 13);                                \
    gll16(_s, _l);                                                           \
    gll16(_s + 131072, _l + 4096);                                           \
} while (0)

#define RD_A(D, MH) do {                                                     \
    const short* _p = Als + (((D) * 2 + (MH)) << 13) + aBase;                \
    _Pragma("unroll")                                                        \
    for (int _fm = 0; _fm < 4; ++_fm) {                                      \
        af[_fm][0] = *(const s16x8*)(_p + _fm * 1024 + slot0);               \
        af[_fm][1] = *(const s16x8*)(_p + _fm * 1024 + (slot0 ^ 32));        \
    }                                                                        \
} while (0)

#define RD_B(D, NH, dst) do {                                                \
    const short* _p = Bls + (((D) * 2 + (NH)) << 13) + bBase;                \
    _Pragma("unroll")                                                        \
    for (int _fn = 0; _fn < 2; ++_fn) {                                      \
        dst[_fn][0] = *(const s16x8*)(_p + _fn * 1024 + slot0);              \
        dst[_fn][1] = *(const s16x8*)(_p + _fn * 1024 + (slot0 ^ 32));       \
    }                                                                        \
} while (0)

#define MM(MH, NH, bv) do {                                                  \
    __builtin_amdgcn_s_setprio(1);                                           \
    _Pragma("unroll")                                                        \
    for (int _fm = 0; _fm < 4; ++_fm) {                                      \
        _Pragma("unroll")                                                    \
        for (int _fn = 0; _fn < 2; ++_fn) {                                  \
            _Pragma("unroll")                                                \
            for (int _kk = 0; _kk < 2; ++_kk)                                \
                acc[(MH) * 4 + _fm][(NH) * 2 + _fn] =                        \
                    mfma16(af[_fm][_kk], bv[_fn][_kk],                       \
                           acc[(MH) * 4 + _fm][(NH) * 2 + _fn]);             \
        }                                                                    \
    }                                                                        \
    __builtin_amdgcn_s_setprio(0);                                           \
} while (0)

#define VM4 asm volatile("s_waitcnt vmcnt(4)" ::: "memory")
#define VM0 asm volatile("s_waitcnt vmcnt(0)" ::: "memory")

#define TILE(D, T, S1, S2, VMST) do {                                        \
    /* P1 (M0,N0) */                                                         \
    RD_A(D, 0); RD_B(D, 0, bv0);                                             \
    if (S1) STAGE_A(1 - (D), 1, (T) + 1);                                    \
    SB0; BARM; SB0; LGKM0; SB0;                                              \
    MM(0, 0, bv0);                                                           \
    SB0; BARM; SB0;                                                          \
    /* P2 (M0,N1) */                                                         \
    RD_B(D, 1, bv1);                                                         \
    if (S1) STAGE_B(1 - (D), 1, (T) + 1);                                    \
    SB0; BARM; SB0; LGKM0; SB0;                                              \
    MM(0, 1, bv1);                                                           \
    SB0; BARM; SB0;                                                          \
    /* P3 (M1,N1) */                                                         \
    RD_A(D, 1);                                                              \
    if (S2) STAGE_A((D), 0, (T) + 2);                                        \
    SB0; BARM; SB0; LGKM0; SB0;                                              \
    MM(1, 1, bv1);                                                           \
    SB0; BARM; SB0;                                                          \
    /* P4 (M1,N0) */                                                         \
    if (S2) STAGE_B((D), 0, (T) + 2);                                        \
    SB0; BARM; SB0;                                                          \
    MM(1, 0, bv0);                                                           \
    SB0; VMST; BARM; SB0;                                                    \
} while (0)

__global__ __launch_bounds__(512, 2) void gemm256(const short* __restrict__ X,
                                                  const short* __restrict__ Bt,
                                                  short* __restrict__ C) {
    __shared__ __align__(16) short Als[32768];   // 64 KiB
    __shared__ __align__(16) short Bls[32768];   // 64 KiB

    const int t    = threadIdx.x;
    const int lane = t & 63;
    const int w    = t >> 6;          // wave 0..7
    const int wm   = w >> 2;          // 0..1
    const int wn   = w & 3;           // 0..3
    const int r15  = lane & 15;
    const int q    = lane >> 4;       // 0..3
    const int m0   = blockIdx.y << 8;
    const int n0   = blockIdx.x << 8;

    // ---- staging geometry (rotation-permuted global source, linear LDS dest)
    const int srow = t >> 3;                                  // 0..63
    const int kc8  = (((t & 7) - srow) & 7) * 8;              // rotated k-chunk
    const short* Agp = X + (size_t)(m0 + srow) * 1024 + kc8;  // +h*65536 +kt*64
    const int rB0  = ((srow >> 5) << 6) | (srow & 31);
    const short* Bgp = Bt + (size_t)(n0 + rB0) * 1024 + kc8;
    short* lA = Als + t * 8;
    short* lB = Bls + t * 8;

    // ---- fragment-read geometry (rotated slots)
    const int slot0 = ((q + r15) & 7) * 8;                    // kk=0; kk=1 -> ^32
    const int aBase = (wm * 64 + r15) * 64;                   // + fm*1024
    const int bBase = (wn * 32 + r15) * 64;                   // + fn*1024

    f32x4 acc[8][4] = {};
    s16x8 af[4][2], bv0[2][2], bv1[2][2];

    // prologue: T0 complete + T1 h0 halves; wait all of T0 (T1-h0 in flight)
    STAGE_A(0, 0, 0); STAGE_A(0, 1, 0); STAGE_B(0, 0, 0); STAGE_B(0, 1, 0);
    STAGE_A(1, 0, 1); STAGE_B(1, 0, 1);
    VM4;
    BARM; SB0;

#pragma unroll 1
    for (int it = 0; it < 7; ++it) {
        const int T = it * 2;
        TILE(0, T,     true, true, VM4);
        TILE(1, T + 1, true, true, VM4);
    }
    TILE(0, 14, true,  false, VM0);   // stages h1(15) only; drain before last
    TILE(1, 15, false, false, (void)0);

    // epilogue: D col = lane&15, row = q*4 + reg
#pragma unroll
    for (int fmt = 0; fmt < 8; ++fmt) {
        const int rbase = m0 + wm * 128 + fmt * 16 + q * 4;
#pragma unroll
        for (int r = 0; r < 4; ++r) {
            size_t rowoff = (size_t)(rbase + r) * 6144;
#pragma unroll
            for (int fnt = 0; fnt < 4; ++fnt) {
                int col = n0 + wn * 64 + fnt * 16 + r15;
                C[rowoff + col] = f2bf(acc[fmt][fnt][r]);
            }
        }
    }
}

// ---------------------------------------------------------------------------
// Final 1x1 conv (unchanged this round).
__global__ __launch_bounds__(256, 2) void final_gemm2(const float* __restrict__ x,
                                                      const short* __restrict__ H,
                                                      const float* __restrict__ W,
                                                      const float* __restrict__ bias,
                                                      float* __restrict__ out) {
    __shared__ __align__(16) short Wl[64 * 40];
    __shared__ __align__(16) short Hl[384 * 40];

    const int t  = threadIdx.x;
    const int lane = t & 63;
    const int wv   = t >> 6;
    const int lane15 = lane & 15;
    const int lq     = lane >> 4;
    const int n  = blockIdx.y;
    const int v0 = blockIdx.x * 32;
    const int p0 = v0 * 12;

    const int hc    = t & 31;
    const int hw    = t >> 5;        // 0..7
    const int l_lo  = hw & 1;
    const int lane4 = hw >> 1;       // 0..3  (constant per wave)

    f32x4 acc[4][6] = {};

    for (int g = 0; g < 7; ++g) {
        __syncthreads();
        {
            int o = t >> 2, c0 = (t & 3) * 8;
            const float* wp = W + (size_t)o * 224 + g * 32 + c0;
            float4 w0 = *(const float4*)wp;
            float4 w1 = *(const float4*)(wp + 4);
            short* d = &Wl[o * 40 + c0];
            d[0] = f2bf(w0.x); d[1] = f2bf(w0.y); d[2] = f2bf(w0.z); d[3] = f2bf(w0.w);
            d[4] = f2bf(w1.x); d[5] = f2bf(w1.y); d[6] = f2bf(w1.z); d[7] = f2bf(w1.w);
        }
        if (g == 0) {
            int c = t >> 3, j0 = t & 7;
            const float* src = x + ((size_t)n * 32 + c) * 12288 + p0;
#pragma unroll
            for (int it = 0; it < 12; ++it) {
                int ch = j0 + it * 8;          // 0..95
                float4 v = *(const float4*)(src + ch * 4);
                int p = ch * 4;
                Hl[(p + 0) * 40 + c] = f2bf(v.x);
                Hl[(p + 1) * 40 + c] = f2bf(v.y);
                Hl[(p + 2) * 40 + c] = f2bf(v.z);
                Hl[(p + 3) * 40 + c] = f2bf(v.w);
            }
        } else {
            const short* base = H + (size_t)(g - 1) * 1024 + v0 + lane4 * 8;
#pragma unroll
            for (int lt = 0; lt < 6; ++lt) {
                int l = l_lo + 2 * lt;
                size_t row = ((size_t)n * 32 + hc) * 12 + l;
                s16x8 h8 = *(const s16x8*)(base + row * 6144);
#pragma unroll
                for (int i = 0; i < 8; ++i)
                    Hl[((lane4 * 8 + i) * 12 + l) * 40 + hc] = h8[i];
            }
        }
        __syncthreads();

        s16x8 af[4], bf[6];
#pragma unroll
        for (int ot = 0; ot < 4; ++ot)
            af[ot] = *(const s16x8*)&Wl[(ot * 16 + lane15) * 40 + lq * 8];
#pragma unroll
        for (int bt = 0; bt < 6; ++bt)
            bf[bt] = *(const s16x8*)&Hl[(wv * 96 + bt * 16 + lane15) * 40 + lq * 8];
#pragma unroll
        for (int ot = 0; ot < 4; ++ot)
#pragma unroll
            for (int bt = 0; bt < 6; ++bt)
                acc[ot][bt] = mfma16(af[ot], bf[bt], acc[ot][bt]);
    }

#pragma unroll
    for (int ot = 0; ot < 4; ++ot) {
#pragma unroll
        for (int r = 0; r < 4; ++r) {
            int o = ot * 16 + lq * 4 + r;
            float bo = bias[o];
            float* op = out + ((size_t)n * 64 + o) * 12288 + p0;
#pragma unroll
            for (int bt = 0; bt < 6; ++bt) {
                int p = wv * 96 + bt * 16 + lane15;
                op[p] = acc[ot][bt][r] + bo;
            }
        }
    }
}

// ---------------------------------------------------------------------------
extern "C" void kernel_launch(void* const* d_in, const int* in_sizes, int n_in,
                              void* d_out, int out_size, void* d_ws, size_t ws_size,
                              hipStream_t stream) {
    const float* x  = (const float*)d_in[0];
    const float* a0 = (const float*)d_in[1];
    const float* a1 = (const float*)d_in[2];
    const float* a2 = (const float*)d_in[3];
    const float* W  = (const float*)d_in[4];
    const float* bs = (const float*)d_in[5];
    float* out = (float*)d_out;

    // workspace (bytes):
    //   Xg    bf16 [24576][1024]   @ 0           50,331,648
    //   Ab    bf16 [3][1024][1024] @ 50331648     6,291,456
    //   Btall bf16 [6][1024][1024] @ 56623104    12,582,912
    //   Hmv   bf16 [24576][6144]   @ 69206016   301,989,888   (ends 371,195,904)
    char* ws = (char*)d_ws;
    short* Xg    = (short*)(ws);
    short* Ab    = (short*)(ws + 50331648L);
    short* Btall = (short*)(ws + 56623104L);
    short* Hmv   = (short*)(ws + 69206016L);

    cast_x_v2<<<2048, 256, 0, stream>>>(x, Xg);
    cast_a_v2<<<dim3(32, 32, 3), 256, 0, stream>>>(a0, a1, a2, Btall, Ab);

    // (A_j^2)^T via small BT-GEMM -> slice 2j+1
    gemm_bt<<<dim3(8, 8, 3), 256, 0, stream>>>(
        Btall, 2097152L, Ab, 1048576L, Btall + 1048576L, 2097152L, 1024);

    // all 6 diffusion outputs in one 8-phase 256^2 GEMM: Hmv[m][s*1024+v]
    gemm256<<<dim3(24, 96), 512, 0, stream>>>(Xg, Btall, Hmv);

    final_gemm2<<<dim3(32, 64), 256, 0, stream>>>(x, Hmv, W, bs, out);
}

// Round 3
// 745.758 us; speedup vs baseline: 1.2367x; 1.0628x over previous
//
#include <hip/hip_runtime.h>
#include <hip/hip_bf16.h>

// B=64, C=32, V=1024, L=12, C_OUT=64, C_CAT=224
// M = B*C*L = 24576 rows; N = 6 slices * 1024 = 6144 cols; K = 1024.
// Row order m' = (b*12 + l)*32 + c  (so 32 consecutive rows = one (b,l) group).
// Slice order s: 0=A0^T, 1=(A0^2)^T, 2=A1^T, 3=(A1^2)^T, 4=A2^T, 5=(A2^2)^T
// Hcat[R][k]: R = b*12288 + v*12 + l, k = s*32 + c  (192 wide, bf16).
// Final conv: out[b,o,p] = bias[o] + sum_c W[o][c] x[b,c,p] + sum_k W[o][32+k] Hcat[R][k].

typedef __attribute__((ext_vector_type(4))) float  f32x4;
typedef __attribute__((ext_vector_type(8))) short  s16x8;
typedef __attribute__((ext_vector_type(4))) short  s16x4;

__device__ inline short f2bf(float f) {
    unsigned u = __builtin_bit_cast(unsigned, f);
    unsigned r = (u + 0x7FFFu + ((u >> 16) & 1u)) >> 16;   // RNE
    return (short)r;
}

__device__ inline f32x4 mfma16(s16x8 a, s16x8 b, f32x4 c) {
    return __builtin_amdgcn_mfma_f32_16x16x32_bf16(a, b, c, 0, 0, 0);
}

__device__ inline void gll16(const void* g, void* l) {
    __builtin_amdgcn_global_load_lds(
        (const __attribute__((address_space(1))) void*)g,
        (__attribute__((address_space(3))) void*)l, 16, 0, 0);
}

#define SB0   __builtin_amdgcn_sched_barrier(0)
#define BARM  asm volatile("s_barrier" ::: "memory")
#define LGKM0 asm volatile("s_waitcnt lgkmcnt(0)" ::: "memory")

// ---------------------------------------------------------------------------
// x [B,C,V,L] fp32 -> Xg bf16 [(b*12+l)*32 + c][v].  One block per bc slab.
__global__ __launch_bounds__(256) void cast_x_v2(const float* __restrict__ x,
                                                 short* __restrict__ Xg) {
    __shared__ short Xl[12 * 1040];
    const int bc = blockIdx.x;
    const int t  = threadIdx.x;
    const int b  = bc >> 5;
    const int c  = bc & 31;
    const float4* src = (const float4*)(x + (size_t)bc * 12288);
#pragma unroll
    for (int k = 0; k < 12; ++k) {
        int f4 = k * 256 + t;                 // 0..3071
        float4 v = src[f4];
        int f  = f4 * 4;
        int vi = f / 12;
        int li = f - vi * 12;
        float vals[4] = {v.x, v.y, v.z, v.w};
#pragma unroll
        for (int e = 0; e < 4; ++e) {
            Xl[li * 1040 + vi] = f2bf(vals[e]);
            if (++li == 12) { li = 0; ++vi; }
        }
    }
    __syncthreads();
#pragma unroll
    for (int k = 0; k < 6; ++k) {
        int ch = k * 256 + t;                 // 0..1535
        int l  = ch >> 7;
        int v8 = ch & 127;
        *(s16x8*)(Xg + (size_t)(b * 384 + l * 32 + c) * 1024 + v8 * 8) =
            *(const s16x8*)&Xl[l * 1040 + v8 * 8];
    }
}

// ---------------------------------------------------------------------------
// A_j [v][w] fp32 -> At_j bf16 [w][v] (into Bt_all slice 2j)  +  Ab_j bf16 [v][w]
__global__ __launch_bounds__(256) void cast_a_v2(const float* __restrict__ a0,
                                                 const float* __restrict__ a1,
                                                 const float* __restrict__ a2,
                                                 short* __restrict__ Btall,
                                                 short* __restrict__ Ab) {
    __shared__ float tbuf[32][33];
    const int z = blockIdx.z;
    const float* A = (z == 0) ? a0 : ((z == 1) ? a1 : a2);
    const int v0 = blockIdx.x * 32;
    const int w0 = blockIdx.y * 32;
    const int tr = threadIdx.x >> 3;
    const int tc = (threadIdx.x & 7) << 2;
    float4 val = *(const float4*)&A[(size_t)(v0 + tr) * 1024 + w0 + tc];
    s16x4 sb;
    sb[0] = f2bf(val.x); sb[1] = f2bf(val.y); sb[2] = f2bf(val.z); sb[3] = f2bf(val.w);
    *(s16x4*)(Ab + (size_t)z * 1048576 + (size_t)(v0 + tr) * 1024 + w0 + tc) = sb;
    tbuf[tr][tc + 0] = val.x; tbuf[tr][tc + 1] = val.y;
    tbuf[tr][tc + 2] = val.z; tbuf[tr][tc + 3] = val.w;
    __syncthreads();
    s16x4 st;
#pragma unroll
    for (int i = 0; i < 4; ++i) st[i] = f2bf(tbuf[tc + i][tr]);
    *(s16x4*)(Btall + (size_t)(2 * z) * 1048576 + (size_t)(w0 + tr) * 1024 + v0 + tc) = st;
}

// ---------------------------------------------------------------------------
// Small BT-GEMM (A^2 step): 128x128 tile, BK=32, m97 structure.
__global__ __launch_bounds__(256, 2) void gemm_bt(const short* __restrict__ Xb, long xz,
                                                  const short* __restrict__ Btb, long bz,
                                                  short* __restrict__ Cb, long cz,
                                                  int crow) {
    __shared__ __align__(16) short Alds[128 * 32];
    __shared__ __align__(16) short Blds[128 * 32];

    const int tid  = threadIdx.x;
    const int lane = tid & 63;
    const int wid  = tid >> 6;
    const int wm   = wid >> 1;
    const int wn   = wid & 1;
    const int m0   = blockIdx.y * 128;
    const int n0   = blockIdx.x * 128;

    const short* X  = Xb  + (size_t)blockIdx.z * xz;
    const short* Bt = Btb + (size_t)blockIdx.z * bz;
    short*       C  = Cb  + (size_t)blockIdx.z * cz;

    const short* Ag = X  + (size_t)(m0 + wid * 32 + (lane >> 2)) * 1024 + (lane & 3) * 8;
    const short* Bg = Bt + (size_t)(n0 + wid * 32 + (lane >> 2)) * 1024 + (lane & 3) * 8;
    short* la = &Alds[wid * 1024];
    short* lb = &Blds[wid * 1024];

    const int lane15 = lane & 15;
    const int lq     = lane >> 4;
    const int ar     = lane15 * 32 + lq * 8;

    f32x4 acc[4][4] = {};

    for (int k0 = 0; k0 < 1024; k0 += 32) {
        __syncthreads();
        gll16(Ag + k0, la);
        gll16(Ag + k0 + 16 * 1024, la + 512);
        gll16(Bg + k0, lb);
        gll16(Bg + k0 + 16 * 1024, lb + 512);
        __syncthreads();

        s16x8 af[4], bf[4];
#pragma unroll
        for (int i = 0; i < 4; ++i)
            af[i] = *(const s16x8*)&Alds[(wm * 64 + i * 16) * 32 + ar];
#pragma unroll
        for (int j = 0; j < 4; ++j)
            bf[j] = *(const s16x8*)&Blds[(wn * 64 + j * 16) * 32 + ar];
#pragma unroll
        for (int i = 0; i < 4; ++i)
#pragma unroll
            for (int j = 0; j < 4; ++j)
                acc[i][j] = mfma16(af[i], bf[j], acc[i][j]);
    }

#pragma unroll
    for (int i = 0; i < 4; ++i) {
        int rbase = m0 + wm * 64 + i * 16 + lq * 4;
#pragma unroll
        for (int r = 0; r < 4; ++r) {
            size_t rowoff = (size_t)(rbase + r) * crow;
#pragma unroll
            for (int j = 0; j < 4; ++j) {
                int col = n0 + wn * 64 + j * 16 + lane15;
                C[rowoff + col] = f2bf(acc[i][j][r]);
            }
        }
    }
}

// ---------------------------------------------------------------------------
// Main GEMM: 256x256 tile, BK=64, 8 waves (2Mx4N), 8-phase counted-vmcnt
// schedule with rotation-swizzled LDS (verified r2: 0 bank conflicts).
// Core loop IDENTICAL to r2; only the epilogue changed (writes Hcat layout).

#define STAGE_A(d, h, kt) do {                                               \
    const short* _s = Agp + (h) * 65536 + (kt) * 64;                         \
    short* _l = lA + (((d) * 2 + (h)) << 13);                                \
    gll16(_s, _l);                                                           \
    gll16(_s + 131072, _l + 4096);                                           \
} while (0)

#define STAGE_B(d, h, kt) do {                                               \
    const short* _s = Bgp + (h) * 32768 + (kt) * 64;                         \
    short* _l = lB + (((d) * 2 + (h)) << 13);                                \
    gll16(_s, _l);                                                           \
    gll16(_s + 131072, _l + 4096);                                           \
} while (0)

#define RD_A(D, MH) do {                                                     \
    const short* _p = Als + (((D) * 2 + (MH)) << 13) + aBase;                \
    _Pragma("unroll")                                                        \
    for (int _fm = 0; _fm < 4; ++_fm) {                                      \
        af[_fm][0] = *(const s16x8*)(_p + _fm * 1024 + slot0);               \
        af[_fm][1] = *(const s16x8*)(_p + _fm * 1024 + (slot0 ^ 32));        \
    }                                                                        \
} while (0)

#define RD_B(D, NH, dst) do {                                                \
    const short* _p = Bls + (((D) * 2 + (NH)) << 13) + bBase;                \
    _Pragma("unroll")                                                        \
    for (int _fn = 0; _fn < 2; ++_fn) {                                      \
        dst[_fn][0] = *(const s16x8*)(_p + _fn * 1024 + slot0);              \
        dst[_fn][1] = *(const s16x8*)(_p + _fn * 1024 + (slot0 ^ 32));       \
    }                                                                        \
} while (0)

#define MM(MH, NH, bv) do {                                                  \
    __builtin_amdgcn_s_setprio(1);                                           \
    _Pragma("unroll")                                                        \
    for (int _fm = 0; _fm < 4; ++_fm) {                                      \
        _Pragma("unroll")                                                    \
        for (int _fn = 0; _fn < 2; ++_fn) {                                  \
            _Pragma("unroll")                                                \
            for (int _kk = 0; _kk < 2; ++_kk)                                \
                acc[(MH) * 4 + _fm][(NH) * 2 + _fn] =                        \
                    mfma16(af[_fm][_kk], bv[_fn][_kk],                       \
                           acc[(MH) * 4 + _fm][(NH) * 2 + _fn]);             \
        }                                                                    \
    }                                                                        \
    __builtin_amdgcn_s_setprio(0);                                           \
} while (0)

#define VM4 asm volatile("s_waitcnt vmcnt(4)" ::: "memory")
#define VM0 asm volatile("s_waitcnt vmcnt(0)" ::: "memory")

#define TILE(D, T, S1, S2, VMST) do {                                        \
    /* P1 (M0,N0) */                                                         \
    RD_A(D, 0); RD_B(D, 0, bv0);                                             \
    if (S1) STAGE_A(1 - (D), 1, (T) + 1);                                    \
    SB0; BARM; SB0; LGKM0; SB0;                                              \
    MM(0, 0, bv0);                                                           \
    SB0; BARM; SB0;                                                          \
    /* P2 (M0,N1) */                                                         \
    RD_B(D, 1, bv1);                                                         \
    if (S1) STAGE_B(1 - (D), 1, (T) + 1);                                    \
    SB0; BARM; SB0; LGKM0; SB0;                                              \
    MM(0, 1, bv1);                                                           \
    SB0; BARM; SB0;                                                          \
    /* P3 (M1,N1) */                                                         \
    RD_A(D, 1);                                                              \
    if (S2) STAGE_A((D), 0, (T) + 2);                                        \
    SB0; BARM; SB0; LGKM0; SB0;                                              \
    MM(1, 1, bv1);                                                           \
    SB0; BARM; SB0;                                                          \
    /* P4 (M1,N0) */                                                         \
    if (S2) STAGE_B((D), 0, (T) + 2);                                        \
    SB0; BARM; SB0;                                                          \
    MM(1, 0, bv0);                                                           \
    SB0; VMST; BARM; SB0;                                                    \
} while (0)

__global__ __launch_bounds__(512, 2) void gemm256(const short* __restrict__ X,
                                                  const short* __restrict__ Bt,
                                                  short* __restrict__ C) {
    __shared__ __align__(16) short Als[32768];   // 64 KiB
    __shared__ __align__(16) short Bls[32768];   // 64 KiB

    const int t    = threadIdx.x;
    const int lane = t & 63;
    const int w    = t >> 6;          // wave 0..7
    const int wm   = w >> 2;          // 0..1
    const int wn   = w & 3;           // 0..3
    const int r15  = lane & 15;
    const int q    = lane >> 4;       // 0..3
    const int m0   = blockIdx.y << 8;
    const int n0   = blockIdx.x << 8;

    // staging geometry (rotation-permuted global source, linear LDS dest)
    const int srow = t >> 3;                                  // 0..63
    const int kc8  = (((t & 7) - srow) & 7) * 8;              // rotated k-chunk
    const short* Agp = X + (size_t)(m0 + srow) * 1024 + kc8;
    const int rB0  = ((srow >> 5) << 6) | (srow & 31);
    const short* Bgp = Bt + (size_t)(n0 + rB0) * 1024 + kc8;
    short* lA = Als + t * 8;
    short* lB = Bls + t * 8;

    // fragment-read geometry (rotated slots)
    const int slot0 = ((q + r15) & 7) * 8;                    // kk=0; kk=1 -> ^32
    const int aBase = (wm * 64 + r15) * 64;                   // + fm*1024
    const int bBase = (wn * 32 + r15) * 64;                   // + fn*1024

    f32x4 acc[8][4] = {};
    s16x8 af[4][2], bv0[2][2], bv1[2][2];

    // prologue: T0 complete + T1 h0 halves
    STAGE_A(0, 0, 0); STAGE_A(0, 1, 0); STAGE_B(0, 0, 0); STAGE_B(0, 1, 0);
    STAGE_A(1, 0, 1); STAGE_B(1, 0, 1);
    VM4;
    BARM; SB0;

#pragma unroll 1
    for (int it = 0; it < 7; ++it) {
        const int T = it * 2;
        TILE(0, T,     true, true, VM4);
        TILE(1, T + 1, true, true, VM4);
    }
    TILE(0, 14, true,  false, VM0);
    TILE(1, 15, false, false, (void)0);

    // ---- epilogue: scatter into Hcat[R][192], R = b*12288 + v*12 + l.
    // D-tile row m' = m0 + wm*128 + fmt*16 + q*4 + r  (r = acc reg, = c offset)
    //   => group gidx = m0/32 + wm*4 + (fmt>>1) = b*12 + l;  c = (fmt&1)*16+q*4+r
    // D-tile col = n0 + wn*64 + fnt*16 + r15 = s*1024 + v
    // 4 consecutive c per lane -> one s16x4 (8 B) store.
    const int s_idx  = n0 >> 10;
    const int v_base = (n0 & 1023) + wn * 64 + r15;
    const int ks0    = s_idx * 32 + q * 4;
#pragma unroll
    for (int fmt = 0; fmt < 8; ++fmt) {
        const int gidx = (m0 >> 5) + wm * 4 + (fmt >> 1);
        const int bb   = gidx / 12;
        const int ll   = gidx - bb * 12;
        const int ks   = ks0 + (fmt & 1) * 16;
        const size_t base = (size_t)bb * 12288 + ll;
#pragma unroll
        for (int fnt = 0; fnt < 4; ++fnt) {
            const int v = v_base + fnt * 16;
            s16x4 sv;
            sv[0] = f2bf(acc[fmt][fnt][0]);
            sv[1] = f2bf(acc[fmt][fnt][1]);
            sv[2] = f2bf(acc[fmt][fnt][2]);
            sv[3] = f2bf(acc[fmt][fnt][3]);
            *(s16x4*)(C + (base + (size_t)v * 12) * 192 + ks) = sv;
        }
    }
}

// ---------------------------------------------------------------------------
// Final conv as streaming BT-GEMM: out[o][R] = bias[o] + sum_k W[o][k]*Acat[R][k]
// Acat row R = [ x[b,:,p] (32, from fp32 x) | Hcat[R][0..192) ].  K = 7 steps of 32.
// 256 threads (4 waves), R-tile 256 (one b per block), W LDS-resident,
// 3-buffer gll pipeline with counted vmcnt; rotation-swizzled LDS chunks.
__global__ __launch_bounds__(256, 2) void gemm_fin(const float* __restrict__ x,
                                                   const short* __restrict__ Hc,
                                                   const float* __restrict__ W,
                                                   const float* __restrict__ bias,
                                                   float* __restrict__ out) {
    __shared__ __align__(16) short Wl[64 * 232];     // 29.7 KB, rows padded to 232
    __shared__ __align__(16) short Hl[3][8192];      // 3 x 16 KB k-slice buffers

    const int t    = threadIdx.x;
    const int lane = t & 63;
    const int wv   = t >> 6;        // 0..3
    const int r15  = lane & 15;
    const int lq   = lane >> 4;     // 0..3
    const int blk  = blockIdx.x;
    const int b    = blk / 48;                  // 12288/256 = 48 tiles per b
    const int p0   = (blk - b * 48) * 256;
    const size_t R0 = (size_t)b * 12288 + p0;

    // ---- prologue: stage W (fp32 -> bf16), rows padded 224->232 (conflict-free)
    {
        const int o  = t >> 2;
        const int c0 = (t & 3) * 56;
        const float* wp = W + o * 224 + c0;
        short* d = &Wl[o * 232 + c0];
#pragma unroll
        for (int i = 0; i < 14; ++i) {
            float4 w4 = *(const float4*)(wp + i * 4);
            s16x4 s;
            s[0] = f2bf(w4.x); s[1] = f2bf(w4.y); s[2] = f2bf(w4.z); s[3] = f2bf(w4.w);
            *(s16x4*)(d + i * 4) = s;
        }
    }
    // ---- stage step-0 (x, k=c) into Hl[0] with rotated chunks:
    // value (row, c) stored at row*32 + (((c>>3)+(row>>1))&3)*8 + (c&7)
    {
        const int c  = t & 31;
        const int pc = t >> 5;                  // 0..7
        const float* xp = x + ((size_t)b * 32 + c) * 12288 + p0 + pc * 32;
        const int kc = c >> 3, ko = c & 7;
#pragma unroll
        for (int j4 = 0; j4 < 8; ++j4) {
            float4 v = *(const float4*)(xp + j4 * 4);
            float vals[4] = {v.x, v.y, v.z, v.w};
#pragma unroll
            for (int e = 0; e < 4; ++e) {
                int row = pc * 32 + j4 * 4 + e;
                Hl[0][row * 32 + (((kc + (row >> 1)) & 3) << 3) + ko] = f2bf(vals[e]);
            }
        }
    }
    // ---- gll staging: granule G = i*256+t -> row=G>>2, slot=G&3 holds
    // chunk kc=(slot-(row>>1))&3 of Hcat row R0+row, k-slice (step-1).
    const int grow = t >> 2;
    const int slot = t & 3;
#define GLLSTEP(step, buf) do {                                              \
    _Pragma("unroll")                                                        \
    for (int _i = 0; _i < 4; ++_i) {                                         \
        int _row = _i * 64 + grow;                                           \
        int _kc  = (slot - (_row >> 1)) & 3;                                 \
        gll16(Hc + (R0 + _row) * 192 + ((step) - 1) * 32 + _kc * 8,          \
              &Hl[buf][(_i * 256 + t) * 8]);                                 \
    }                                                                        \
} while (0)

    GLLSTEP(1, 1);
    GLLSTEP(2, 2);
    LGKM0;          // ds_writes (W, x) visible
    BARM; SB0;

    f32x4 acc[4][4] = {};

#define FINSTEP(s, buf) do {                                                 \
    s16x8 af[4], bfr[4];                                                     \
    _Pragma("unroll")                                                        \
    for (int _ot = 0; _ot < 4; ++_ot)                                        \
        af[_ot] = *(const s16x8*)&Wl[(_ot * 16 + r15) * 232 + (s) * 32 + lq * 8]; \
    _Pragma("unroll")                                                        \
    for (int _bt = 0; _bt < 4; ++_bt) {                                      \
        int _row = wv * 64 + _bt * 16 + r15;                                 \
        bfr[_bt] = *(const s16x8*)&Hl[buf][_row * 32 + ((((lq) + (_row >> 1)) & 3) << 3)]; \
    }                                                                        \
    _Pragma("unroll")                                                        \
    for (int _ot = 0; _ot < 4; ++_ot) {                                      \
        _Pragma("unroll")                                                    \
        for (int _bt = 0; _bt < 4; ++_bt)                                    \
            acc[_ot][_bt] = mfma16(af[_ot], bfr[_bt], acc[_ot][_bt]);        \
    }                                                                        \
} while (0)

#define VMW(n) asm volatile("s_waitcnt vmcnt(" #n ")" ::: "memory")

    FINSTEP(0, 0);
    BARM; SB0; GLLSTEP(3, 0);
    VMW(8); BARM; SB0;
    FINSTEP(1, 1);
    BARM; SB0; GLLSTEP(4, 1);
    VMW(8); BARM; SB0;
    FINSTEP(2, 2);
    BARM; SB0; GLLSTEP(5, 2);
    VMW(8); BARM; SB0;
    FINSTEP(3, 0);
    BARM; SB0; GLLSTEP(6, 0);
    VMW(8); BARM; SB0;
    FINSTEP(4, 1);
    BARM; SB0;
    VMW(4); BARM; SB0;
    FINSTEP(5, 2);
    BARM; SB0;
    VMW(0); BARM; SB0;
    FINSTEP(6, 0);

    // ---- epilogue: out[(b*64+o)*12288 + p0 + col], col = wv*64+bt*16+r15
#pragma unroll
    for (int ot = 0; ot < 4; ++ot) {
#pragma unroll
        for (int r = 0; r < 4; ++r) {
            const int o = ot * 16 + lq * 4 + r;
            const float bo = bias[o];
            float* op = out + ((size_t)b * 64 + o) * 12288 + p0;
#pragma unroll
            for (int bt = 0; bt < 4; ++bt)
                op[wv * 64 + bt * 16 + r15] = acc[ot][bt][r] + bo;
        }
    }
}

// ---------------------------------------------------------------------------
extern "C" void kernel_launch(void* const* d_in, const int* in_sizes, int n_in,
                              void* d_out, int out_size, void* d_ws, size_t ws_size,
                              hipStream_t stream) {
    const float* x  = (const float*)d_in[0];
    const float* a0 = (const float*)d_in[1];
    const float* a1 = (const float*)d_in[2];
    const float* a2 = (const float*)d_in[3];
    const float* W  = (const float*)d_in[4];
    const float* bs = (const float*)d_in[5];
    float* out = (float*)d_out;

    // workspace (bytes):
    //   Xg    bf16 [24576][1024]   @ 0           50,331,648
    //   Ab    bf16 [3][1024][1024] @ 50331648     6,291,456
    //   Btall bf16 [6][1024][1024] @ 56623104    12,582,912
    //   Hcat  bf16 [786432][192]   @ 69206016   301,989,888   (ends 371,195,904)
    char* ws = (char*)d_ws;
    short* Xg    = (short*)(ws);
    short* Ab    = (short*)(ws + 50331648L);
    short* Btall = (short*)(ws + 56623104L);
    short* Hcat  = (short*)(ws + 69206016L);

    cast_x_v2<<<2048, 256, 0, stream>>>(x, Xg);
    cast_a_v2<<<dim3(32, 32, 3), 256, 0, stream>>>(a0, a1, a2, Btall, Ab);

    // (A_j^2)^T via small BT-GEMM -> slice 2j+1
    gemm_bt<<<dim3(8, 8, 3), 256, 0, stream>>>(
        Btall, 2097152L, Ab, 1048576L, Btall + 1048576L, 2097152L, 1024);

    // all 6 diffusion outputs: Hcat[R][s*32+c]
    gemm256<<<dim3(24, 96), 512, 0, stream>>>(Xg, Btall, Hcat);

    // fused 1x1 conv (x handled as k-step 0 directly from fp32)
    gemm_fin<<<3072, 256, 0, stream>>>(x, Hcat, W, bs, out);
}

// Round 4
// 720.211 us; speedup vs baseline: 1.2805x; 1.0355x over previous
//
#include <hip/hip_runtime.h>
#include <hip/hip_bf16.h>

// B=64, C=32, V=1024, L=12, C_OUT=64, C_CAT=224
// M = B*C*L = 24576 rows; N = 6 slices * 1024 = 6144 cols; K = 1024.
// Row order m' = (b*12 + l)*32 + c  (so 32 consecutive rows = one (b,l) group).
// Slice order s: 0=A0^T, 1=(A0^2)^T, 2=A1^T, 3=(A1^2)^T, 4=A2^T, 5=(A2^2)^T
// Hcat[R][k]: R = b*12288 + v*12 + l, k = s*32 + c  (192 wide, bf16).
// Final conv: out[b,o,p] = bias[o] + sum_c W[o][c] x[b,c,p] + sum_k W[o][32+k] Hcat[R][k].

typedef __attribute__((ext_vector_type(4))) float  f32x4;
typedef __attribute__((ext_vector_type(8))) short  s16x8;
typedef __attribute__((ext_vector_type(4))) short  s16x4;

__device__ inline short f2bf(float f) {
    unsigned u = __builtin_bit_cast(unsigned, f);
    unsigned r = (u + 0x7FFFu + ((u >> 16) & 1u)) >> 16;   // RNE
    return (short)r;
}

__device__ inline f32x4 mfma16(s16x8 a, s16x8 b, f32x4 c) {
    return __builtin_amdgcn_mfma_f32_16x16x32_bf16(a, b, c, 0, 0, 0);
}

__device__ inline void gll16(const void* g, void* l) {
    __builtin_amdgcn_global_load_lds(
        (const __attribute__((address_space(1))) void*)g,
        (__attribute__((address_space(3))) void*)l, 16, 0, 0);
}

#define SB0   __builtin_amdgcn_sched_barrier(0)
#define BARM  asm volatile("s_barrier" ::: "memory")
#define LGKM0 asm volatile("s_waitcnt lgkmcnt(0)" ::: "memory")

// ---------------------------------------------------------------------------
// x [B,C,V,L] fp32 -> Xg bf16 [(b*12+l)*32 + c][v].  One block per bc slab.
__global__ __launch_bounds__(256) void cast_x_v2(const float* __restrict__ x,
                                                 short* __restrict__ Xg) {
    __shared__ short Xl[12 * 1040];
    const int bc = blockIdx.x;
    const int t  = threadIdx.x;
    const int b  = bc >> 5;
    const int c  = bc & 31;
    const float4* src = (const float4*)(x + (size_t)bc * 12288);
#pragma unroll
    for (int k = 0; k < 12; ++k) {
        int f4 = k * 256 + t;                 // 0..3071
        float4 v = src[f4];
        int f  = f4 * 4;
        int vi = f / 12;
        int li = f - vi * 12;
        float vals[4] = {v.x, v.y, v.z, v.w};
#pragma unroll
        for (int e = 0; e < 4; ++e) {
            Xl[li * 1040 + vi] = f2bf(vals[e]);
            if (++li == 12) { li = 0; ++vi; }
        }
    }
    __syncthreads();
#pragma unroll
    for (int k = 0; k < 6; ++k) {
        int ch = k * 256 + t;                 // 0..1535
        int l  = ch >> 7;
        int v8 = ch & 127;
        *(s16x8*)(Xg + (size_t)(b * 384 + l * 32 + c) * 1024 + v8 * 8) =
            *(const s16x8*)&Xl[l * 1040 + v8 * 8];
    }
}

// ---------------------------------------------------------------------------
// A_j [v][w] fp32 -> At_j bf16 [w][v] (into Bt_all slice 2j)  +  Ab_j bf16 [v][w]
__global__ __launch_bounds__(256) void cast_a_v2(const float* __restrict__ a0,
                                                 const float* __restrict__ a1,
                                                 const float* __restrict__ a2,
                                                 short* __restrict__ Btall,
                                                 short* __restrict__ Ab) {
    __shared__ float tbuf[32][33];
    const int z = blockIdx.z;
    const float* A = (z == 0) ? a0 : ((z == 1) ? a1 : a2);
    const int v0 = blockIdx.x * 32;
    const int w0 = blockIdx.y * 32;
    const int tr = threadIdx.x >> 3;
    const int tc = (threadIdx.x & 7) << 2;
    float4 val = *(const float4*)&A[(size_t)(v0 + tr) * 1024 + w0 + tc];
    s16x4 sb;
    sb[0] = f2bf(val.x); sb[1] = f2bf(val.y); sb[2] = f2bf(val.z); sb[3] = f2bf(val.w);
    *(s16x4*)(Ab + (size_t)z * 1048576 + (size_t)(v0 + tr) * 1024 + w0 + tc) = sb;
    tbuf[tr][tc + 0] = val.x; tbuf[tr][tc + 1] = val.y;
    tbuf[tr][tc + 2] = val.z; tbuf[tr][tc + 3] = val.w;
    __syncthreads();
    s16x4 st;
#pragma unroll
    for (int i = 0; i < 4; ++i) st[i] = f2bf(tbuf[tc + i][tr]);
    *(s16x4*)(Btall + (size_t)(2 * z) * 1048576 + (size_t)(w0 + tr) * 1024 + v0 + tc) = st;
}

// ---------------------------------------------------------------------------
// Small BT-GEMM (A^2 step): 128x128 tile, BK=32, m97 structure.
__global__ __launch_bounds__(256, 2) void gemm_bt(const short* __restrict__ Xb, long xz,
                                                  const short* __restrict__ Btb, long bz,
                                                  short* __restrict__ Cb, long cz,
                                                  int crow) {
    __shared__ __align__(16) short Alds[128 * 32];
    __shared__ __align__(16) short Blds[128 * 32];

    const int tid  = threadIdx.x;
    const int lane = tid & 63;
    const int wid  = tid >> 6;
    const int wm   = wid >> 1;
    const int wn   = wid & 1;
    const int m0   = blockIdx.y * 128;
    const int n0   = blockIdx.x * 128;

    const short* X  = Xb  + (size_t)blockIdx.z * xz;
    const short* Bt = Btb + (size_t)blockIdx.z * bz;
    short*       C  = Cb  + (size_t)blockIdx.z * cz;

    const short* Ag = X  + (size_t)(m0 + wid * 32 + (lane >> 2)) * 1024 + (lane & 3) * 8;
    const short* Bg = Bt + (size_t)(n0 + wid * 32 + (lane >> 2)) * 1024 + (lane & 3) * 8;
    short* la = &Alds[wid * 1024];
    short* lb = &Blds[wid * 1024];

    const int lane15 = lane & 15;
    const int lq     = lane >> 4;
    const int ar     = lane15 * 32 + lq * 8;

    f32x4 acc[4][4] = {};

    for (int k0 = 0; k0 < 1024; k0 += 32) {
        __syncthreads();
        gll16(Ag + k0, la);
        gll16(Ag + k0 + 16 * 1024, la + 512);
        gll16(Bg + k0, lb);
        gll16(Bg + k0 + 16 * 1024, lb + 512);
        __syncthreads();

        s16x8 af[4], bf[4];
#pragma unroll
        for (int i = 0; i < 4; ++i)
            af[i] = *(const s16x8*)&Alds[(wm * 64 + i * 16) * 32 + ar];
#pragma unroll
        for (int j = 0; j < 4; ++j)
            bf[j] = *(const s16x8*)&Blds[(wn * 64 + j * 16) * 32 + ar];
#pragma unroll
        for (int i = 0; i < 4; ++i)
#pragma unroll
            for (int j = 0; j < 4; ++j)
                acc[i][j] = mfma16(af[i], bf[j], acc[i][j]);
    }

#pragma unroll
    for (int i = 0; i < 4; ++i) {
        int rbase = m0 + wm * 64 + i * 16 + lq * 4;
#pragma unroll
        for (int r = 0; r < 4; ++r) {
            size_t rowoff = (size_t)(rbase + r) * crow;
#pragma unroll
            for (int j = 0; j < 4; ++j) {
                int col = n0 + wn * 64 + j * 16 + lane15;
                C[rowoff + col] = f2bf(acc[i][j][r]);
            }
        }
    }
}

// ---------------------------------------------------------------------------
// Main GEMM: 256x256 tile, BK=64, 8 waves (2Mx4N), 8-phase counted-vmcnt
// schedule with rotation-swizzled LDS (verified r2: 0 bank conflicts).
// Core loop IDENTICAL to r2/r3.  Epilogue v2: acc -> LDS (Hcat chunk layout,
// rotated) -> coalesced 64B-segment global stores (fixes r3's scatter).

#define STAGE_A(d, h, kt) do {                                               \
    const short* _s = Agp + (h) * 65536 + (kt) * 64;                         \
    short* _l = lA + (((d) * 2 + (h)) << 13);                                \
    gll16(_s, _l);                                                           \
    gll16(_s + 131072, _l + 4096);                                           \
} while (0)

#define STAGE_B(d, h, kt) do {                                               \
    const short* _s = Bgp + (h) * 32768 + (kt) * 64;                         \
    short* _l = lB + (((d) * 2 + (h)) << 13);                                \
    gll16(_s, _l);                                                           \
    gll16(_s + 131072, _l + 4096);                                           \
} while (0)

#define RD_A(D, MH) do {                                                     \
    const short* _p = Als + (((D) * 2 + (MH)) << 13) + aBase;                \
    _Pragma("unroll")                                                        \
    for (int _fm = 0; _fm < 4; ++_fm) {                                      \
        af[_fm][0] = *(const s16x8*)(_p + _fm * 1024 + slot0);               \
        af[_fm][1] = *(const s16x8*)(_p + _fm * 1024 + (slot0 ^ 32));        \
    }                                                                        \
} while (0)

#define RD_B(D, NH, dst) do {                                                \
    const short* _p = Bls + (((D) * 2 + (NH)) << 13) + bBase;                \
    _Pragma("unroll")                                                        \
    for (int _fn = 0; _fn < 2; ++_fn) {                                      \
        dst[_fn][0] = *(const s16x8*)(_p + _fn * 1024 + slot0);              \
        dst[_fn][1] = *(const s16x8*)(_p + _fn * 1024 + (slot0 ^ 32));       \
    }                                                                        \
} while (0)

#define MM(MH, NH, bv) do {                                                  \
    __builtin_amdgcn_s_setprio(1);                                           \
    _Pragma("unroll")                                                        \
    for (int _fm = 0; _fm < 4; ++_fm) {                                      \
        _Pragma("unroll")                                                    \
        for (int _fn = 0; _fn < 2; ++_fn) {                                  \
            _Pragma("unroll")                                                \
            for (int _kk = 0; _kk < 2; ++_kk)                                \
                acc[(MH) * 4 + _fm][(NH) * 2 + _fn] =                        \
                    mfma16(af[_fm][_kk], bv[_fn][_kk],                       \
                           acc[(MH) * 4 + _fm][(NH) * 2 + _fn]);             \
        }                                                                    \
    }                                                                        \
    __builtin_amdgcn_s_setprio(0);                                           \
} while (0)

#define VM4 asm volatile("s_waitcnt vmcnt(4)" ::: "memory")
#define VM0 asm volatile("s_waitcnt vmcnt(0)" ::: "memory")

#define TILE(D, T, S1, S2, VMST) do {                                        \
    /* P1 (M0,N0) */                                                         \
    RD_A(D, 0); RD_B(D, 0, bv0);                                             \
    if (S1) STAGE_A(1 - (D), 1, (T) + 1);                                    \
    SB0; BARM; SB0; LGKM0; SB0;                                              \
    MM(0, 0, bv0);                                                           \
    SB0; BARM; SB0;                                                          \
    /* P2 (M0,N1) */                                                         \
    RD_B(D, 1, bv1);                                                         \
    if (S1) STAGE_B(1 - (D), 1, (T) + 1);                                    \
    SB0; BARM; SB0; LGKM0; SB0;                                              \
    MM(0, 1, bv1);                                                           \
    SB0; BARM; SB0;                                                          \
    /* P3 (M1,N1) */                                                         \
    RD_A(D, 1);                                                              \
    if (S2) STAGE_A((D), 0, (T) + 2);                                        \
    SB0; BARM; SB0; LGKM0; SB0;                                              \
    MM(1, 1, bv1);                                                           \
    SB0; BARM; SB0;                                                          \
    /* P4 (M1,N0) */                                                         \
    if (S2) STAGE_B((D), 0, (T) + 2);                                        \
    SB0; BARM; SB0;                                                          \
    MM(1, 0, bv0);                                                           \
    SB0; VMST; BARM; SB0;                                                    \
} while (0)

__global__ __launch_bounds__(512, 2) void gemm256(const short* __restrict__ X,
                                                  const short* __restrict__ Bt,
                                                  short* __restrict__ C) {
    __shared__ __align__(16) short LDSU[65536];  // 128 KiB (A/B tiles; epilogue union)
    short* const Als = LDSU;
    short* const Bls = LDSU + 32768;

    const int t    = threadIdx.x;
    const int lane = t & 63;
    const int w    = t >> 6;          // wave 0..7
    const int wm   = w >> 2;          // 0..1
    const int wn   = w & 3;           // 0..3
    const int r15  = lane & 15;
    const int q    = lane >> 4;       // 0..3
    const int m0   = blockIdx.y << 8;
    const int n0   = blockIdx.x << 8;

    // staging geometry (rotation-permuted global source, linear LDS dest)
    const int srow = t >> 3;                                  // 0..63
    const int kc8  = (((t & 7) - srow) & 7) * 8;              // rotated k-chunk
    const short* Agp = X + (size_t)(m0 + srow) * 1024 + kc8;
    const int rB0  = ((srow >> 5) << 6) | (srow & 31);
    const short* Bgp = Bt + (size_t)(n0 + rB0) * 1024 + kc8;
    short* lA = Als + t * 8;
    short* lB = Bls + t * 8;

    // fragment-read geometry (rotated slots)
    const int slot0 = ((q + r15) & 7) * 8;                    // kk=0; kk=1 -> ^32
    const int aBase = (wm * 64 + r15) * 64;                   // + fm*1024
    const int bBase = (wn * 32 + r15) * 64;                   // + fn*1024

    f32x4 acc[8][4] = {};
    s16x8 af[4][2], bv0[2][2], bv1[2][2];

    // prologue: T0 complete + T1 h0 halves
    STAGE_A(0, 0, 0); STAGE_A(0, 1, 0); STAGE_B(0, 0, 0); STAGE_B(0, 1, 0);
    STAGE_A(1, 0, 1); STAGE_B(1, 0, 1);
    VM4;
    BARM; SB0;

#pragma unroll 1
    for (int it = 0; it < 7; ++it) {
        const int T = it * 2;
        TILE(0, T,     true, true, VM4);
        TILE(1, T + 1, true, true, VM4);
    }
    TILE(0, 14, true,  false, VM0);
    TILE(1, 15, false, false, (void)0);

    // ---- epilogue v2: acc -> LDS (Hcat chunk layout, per-row rotation) ->
    // coalesced global stores (4 consecutive lanes = one aligned 64B segment).
    // Mapping: c = (fmt&1)*16 + q*4 + r; gidx_local = wm*4+(fmt>>1);
    //          v_local = wn*64+fnt*16+r15; chunk c16 = c>>3; in-chunk = c&7.
    // LDS slot: E[gl*8192 + vl*32 + ((c16+vl)&3)*8 + (q&1)*4]  (rot by vl).
    short* const E = LDSU;
#pragma unroll
    for (int fmt = 0; fmt < 8; ++fmt) {
        const int gl  = wm * 4 + (fmt >> 1);
        const int c16 = (fmt & 1) * 2 + (q >> 1);
#pragma unroll
        for (int fnt = 0; fnt < 4; ++fnt) {
            const int vl = wn * 64 + fnt * 16 + r15;
            s16x4 sv;
            sv[0] = f2bf(acc[fmt][fnt][0]);
            sv[1] = f2bf(acc[fmt][fnt][1]);
            sv[2] = f2bf(acc[fmt][fnt][2]);
            sv[3] = f2bf(acc[fmt][fnt][3]);
            *(s16x4*)&E[gl * 8192 + vl * 32 + (((c16 + vl) & 3) << 3) + ((q & 1) << 2)] = sv;
        }
    }
    __syncthreads();
    const int s_idx = n0 >> 10;
    const int vg0   = n0 & 1023;
    const int g0    = m0 >> 5;
#pragma unroll
    for (int i = 0; i < 16; ++i) {
        const int G   = i * 512 + t;
        const int row = G >> 2;          // 0..2047
        const int c16 = G & 3;
        const int gl  = row >> 8;
        const int vl  = row & 255;
        const int gg  = g0 + gl;
        const int bb  = gg / 12;
        const int ll  = gg - bb * 12;
        s16x8 val = *(const s16x8*)&E[gl * 8192 + vl * 32 + (((c16 + vl) & 3) << 3)];
        *(s16x8*)(C + ((size_t)bb * 12288 + (size_t)(vg0 + vl) * 12 + ll) * 192
                    + s_idx * 32 + c16 * 8) = val;
    }
}

// ---------------------------------------------------------------------------
// Final conv v2: out[o][R] = bias[o] + sum_k W[o][k]*Acat[R][k], 7 k-steps of 32.
// B-fragments (Hcat) loaded DIRECTLY global->VGPR (each lane's fragment is 16
// contiguous bytes) — no LDS, no barriers in the compute loop.  W LDS-resident;
// x (k-step 0) via one-time LDS transpose.  One barrier total.
__global__ __launch_bounds__(256, 2) void gemm_fin(const float* __restrict__ x,
                                                   const short* __restrict__ Hc,
                                                   const float* __restrict__ W,
                                                   const float* __restrict__ bias,
                                                   float* __restrict__ out) {
    __shared__ __align__(16) short Wl[64 * 232];     // 29.7 KB
    __shared__ __align__(16) short Hl0[8192];        // 16 KB (x k-slice)

    const int t    = threadIdx.x;
    const int lane = t & 63;
    const int wv   = t >> 6;        // 0..3
    const int r15  = lane & 15;
    const int lq   = lane >> 4;     // 0..3
    const int blk  = blockIdx.x;
    const int b    = blk / 48;
    const int p0   = (blk - b * 48) * 256;
    const size_t R0 = (size_t)b * 12288 + p0;

    // ---- issue W loads (fp32), then x loads, then all 24 B-fragment loads.
    // In-order vmcnt: waiting for W/x (for the LDS stage) leaves B in flight.
    const int o  = t >> 2;
    const int c0 = (t & 3) * 56;
    const float* wp = W + o * 224 + c0;
    float4 wbuf[14];
#pragma unroll
    for (int i = 0; i < 14; ++i) wbuf[i] = *(const float4*)(wp + i * 4);

    const int xc = t & 31, pc = t >> 5;
    const float* xp = x + ((size_t)b * 32 + xc) * 12288 + p0 + pc * 32;
    float4 xbuf[8];
#pragma unroll
    for (int j = 0; j < 8; ++j) xbuf[j] = *(const float4*)(xp + j * 4);

    const short* hb = Hc + (R0 + wv * 64 + r15) * 192 + lq * 8;
    s16x8 bH[6][4];
#pragma unroll
    for (int s = 0; s < 6; ++s)
#pragma unroll
        for (int bt = 0; bt < 4; ++bt)
            bH[s][bt] = *(const s16x8*)(hb + (size_t)bt * (16 * 192) + s * 32);

    // ---- stage W into LDS (rows padded 224->232)
    {
        short* d = &Wl[o * 232 + c0];
#pragma unroll
        for (int i = 0; i < 14; ++i) {
            s16x4 s4;
            s4[0] = f2bf(wbuf[i].x); s4[1] = f2bf(wbuf[i].y);
            s4[2] = f2bf(wbuf[i].z); s4[3] = f2bf(wbuf[i].w);
            *(s16x4*)(d + i * 4) = s4;
        }
    }
    // ---- stage x k-slice into Hl0, rotated chunks (verified r3 layout):
    // value (row,c) at row*32 + (((c>>3)+(row>>1))&3)*8 + (c&7)
    {
        const int kc = xc >> 3, ko = xc & 7;
#pragma unroll
        for (int j4 = 0; j4 < 8; ++j4) {
            float vals[4] = {xbuf[j4].x, xbuf[j4].y, xbuf[j4].z, xbuf[j4].w};
#pragma unroll
            for (int e = 0; e < 4; ++e) {
                int row = pc * 32 + j4 * 4 + e;
                Hl0[row * 32 + (((kc + (row >> 1)) & 3) << 3) + ko] = f2bf(vals[e]);
            }
        }
    }
    __syncthreads();

    f32x4 acc[4][4] = {};

    // step 0 (x) from LDS
    {
        s16x8 af[4], bfr[4];
#pragma unroll
        for (int ot = 0; ot < 4; ++ot)
            af[ot] = *(const s16x8*)&Wl[(ot * 16 + r15) * 232 + lq * 8];
#pragma unroll
        for (int bt = 0; bt < 4; ++bt) {
            int row = wv * 64 + bt * 16 + r15;
            bfr[bt] = *(const s16x8*)&Hl0[row * 32 + (((lq + (row >> 1)) & 3) << 3)];
        }
#pragma unroll
        for (int ot = 0; ot < 4; ++ot)
#pragma unroll
            for (int bt = 0; bt < 4; ++bt)
                acc[ot][bt] = mfma16(af[ot], bfr[bt], acc[ot][bt]);
    }
    // steps 1..6 (Hcat) from registers
#pragma unroll
    for (int s = 1; s <= 6; ++s) {
        s16x8 af[4];
#pragma unroll
        for (int ot = 0; ot < 4; ++ot)
            af[ot] = *(const s16x8*)&Wl[(ot * 16 + r15) * 232 + s * 32 + lq * 8];
#pragma unroll
        for (int ot = 0; ot < 4; ++ot)
#pragma unroll
            for (int bt = 0; bt < 4; ++bt)
                acc[ot][bt] = mfma16(af[ot], bH[s - 1][bt], acc[ot][bt]);
    }

    // ---- epilogue: out[(b*64+o)*12288 + p0 + col], col = wv*64+bt*16+r15
#pragma unroll
    for (int ot = 0; ot < 4; ++ot) {
#pragma unroll
        for (int r = 0; r < 4; ++r) {
            const int oo = ot * 16 + lq * 4 + r;
            const float bo = bias[oo];
            float* op = out + ((size_t)b * 64 + oo) * 12288 + p0;
#pragma unroll
            for (int bt = 0; bt < 4; ++bt)
                op[wv * 64 + bt * 16 + r15] = acc[ot][bt][r] + bo;
        }
    }
}

// ---------------------------------------------------------------------------
extern "C" void kernel_launch(void* const* d_in, const int* in_sizes, int n_in,
                              void* d_out, int out_size, void* d_ws, size_t ws_size,
                              hipStream_t stream) {
    const float* x  = (const float*)d_in[0];
    const float* a0 = (const float*)d_in[1];
    const float* a1 = (const float*)d_in[2];
    const float* a2 = (const float*)d_in[3];
    const float* W  = (const float*)d_in[4];
    const float* bs = (const float*)d_in[5];
    float* out = (float*)d_out;

    // workspace (bytes):
    //   Xg    bf16 [24576][1024]   @ 0           50,331,648
    //   Ab    bf16 [3][1024][1024] @ 50331648     6,291,456
    //   Btall bf16 [6][1024][1024] @ 56623104    12,582,912
    //   Hcat  bf16 [786432][192]   @ 69206016   301,989,888   (ends 371,195,904)
    char* ws = (char*)d_ws;
    short* Xg    = (short*)(ws);
    short* Ab    = (short*)(ws + 50331648L);
    short* Btall = (short*)(ws + 56623104L);
    short* Hcat  = (short*)(ws + 69206016L);

    cast_x_v2<<<2048, 256, 0, stream>>>(x, Xg);
    cast_a_v2<<<dim3(32, 32, 3), 256, 0, stream>>>(a0, a1, a2, Btall, Ab);

    // (A_j^2)^T via small BT-GEMM -> slice 2j+1
    gemm_bt<<<dim3(8, 8, 3), 256, 0, stream>>>(
        Btall, 2097152L, Ab, 1048576L, Btall + 1048576L, 2097152L, 1024);

    // all 6 diffusion outputs: Hcat[R][s*32+c]
    gemm256<<<dim3(24, 96), 512, 0, stream>>>(Xg, Btall, Hcat);

    // fused 1x1 conv (x as k-step 0; Hcat fragments direct global->reg)
    gemm_fin<<<3072, 256, 0, stream>>>(x, Hcat, W, bs, out);
}

// Round 5
// 692.975 us; speedup vs baseline: 1.3308x; 1.0393x over previous
//
#include <hip/hip_runtime.h>
#include <hip/hip_bf16.h>

// B=64, C=32, V=1024, L=12, C_OUT=64, C_CAT=224
// M = B*C*L = 24576 rows; N = 6 slices * 1024 = 6144 cols; K = 1024.
// Row order m' = (b*12 + l)*32 + c  (so 32 consecutive rows = one (b,l) group).
// Slice order s: 0=A0^T, 1=(A0^2)^T, 2=A1^T, 3=(A1^2)^T, 4=A2^T, 5=(A2^2)^T
// Hcat[R][k]: R = b*12288 + v*12 + l, k = s*32 + c  (192 wide, bf16).
// Final conv: out[b,o,p] = bias[o] + sum_c W[o][c] x[b,c,p] + sum_k W[o][32+k] Hcat[R][k].

typedef __attribute__((ext_vector_type(4))) float  f32x4;
typedef __attribute__((ext_vector_type(8))) short  s16x8;
typedef __attribute__((ext_vector_type(4))) short  s16x4;

__device__ inline short f2bf(float f) {
    unsigned u = __builtin_bit_cast(unsigned, f);
    unsigned r = (u + 0x7FFFu + ((u >> 16) & 1u)) >> 16;   // RNE
    return (short)r;
}

__device__ inline f32x4 mfma16(s16x8 a, s16x8 b, f32x4 c) {
    return __builtin_amdgcn_mfma_f32_16x16x32_bf16(a, b, c, 0, 0, 0);
}

__device__ inline void gll16(const void* g, void* l) {
    __builtin_amdgcn_global_load_lds(
        (const __attribute__((address_space(1))) void*)g,
        (__attribute__((address_space(3))) void*)l, 16, 0, 0);
}

#define SB0   __builtin_amdgcn_sched_barrier(0)
#define BARM  asm volatile("s_barrier" ::: "memory")
#define LGKM0 asm volatile("s_waitcnt lgkmcnt(0)" ::: "memory")

// ---------------------------------------------------------------------------
// x [B,C,V,L] fp32 -> Xg bf16 [(b*12+l)*32 + c][v].  One block per bc slab.
__global__ __launch_bounds__(256) void cast_x_v2(const float* __restrict__ x,
                                                 short* __restrict__ Xg) {
    __shared__ short Xl[12 * 1040];
    const int bc = blockIdx.x;
    const int t  = threadIdx.x;
    const int b  = bc >> 5;
    const int c  = bc & 31;
    const float4* src = (const float4*)(x + (size_t)bc * 12288);
#pragma unroll
    for (int k = 0; k < 12; ++k) {
        int f4 = k * 256 + t;                 // 0..3071
        float4 v = src[f4];
        int f  = f4 * 4;
        int vi = f / 12;
        int li = f - vi * 12;
        float vals[4] = {v.x, v.y, v.z, v.w};
#pragma unroll
        for (int e = 0; e < 4; ++e) {
            Xl[li * 1040 + vi] = f2bf(vals[e]);
            if (++li == 12) { li = 0; ++vi; }
        }
    }
    __syncthreads();
#pragma unroll
    for (int k = 0; k < 6; ++k) {
        int ch = k * 256 + t;                 // 0..1535
        int l  = ch >> 7;
        int v8 = ch & 127;
        *(s16x8*)(Xg + (size_t)(b * 384 + l * 32 + c) * 1024 + v8 * 8) =
            *(const s16x8*)&Xl[l * 1040 + v8 * 8];
    }
}

// ---------------------------------------------------------------------------
// A_j [v][w] fp32 -> At_j bf16 [w][v] (into Bt_all slice 2j)  +  Ab_j bf16 [v][w]
__global__ __launch_bounds__(256) void cast_a_v2(const float* __restrict__ a0,
                                                 const float* __restrict__ a1,
                                                 const float* __restrict__ a2,
                                                 short* __restrict__ Btall,
                                                 short* __restrict__ Ab) {
    __shared__ float tbuf[32][33];
    const int z = blockIdx.z;
    const float* A = (z == 0) ? a0 : ((z == 1) ? a1 : a2);
    const int v0 = blockIdx.x * 32;
    const int w0 = blockIdx.y * 32;
    const int tr = threadIdx.x >> 3;
    const int tc = (threadIdx.x & 7) << 2;
    float4 val = *(const float4*)&A[(size_t)(v0 + tr) * 1024 + w0 + tc];
    s16x4 sb;
    sb[0] = f2bf(val.x); sb[1] = f2bf(val.y); sb[2] = f2bf(val.z); sb[3] = f2bf(val.w);
    *(s16x4*)(Ab + (size_t)z * 1048576 + (size_t)(v0 + tr) * 1024 + w0 + tc) = sb;
    tbuf[tr][tc + 0] = val.x; tbuf[tr][tc + 1] = val.y;
    tbuf[tr][tc + 2] = val.z; tbuf[tr][tc + 3] = val.w;
    __syncthreads();
    s16x4 st;
#pragma unroll
    for (int i = 0; i < 4; ++i) st[i] = f2bf(tbuf[tc + i][tr]);
    *(s16x4*)(Btall + (size_t)(2 * z) * 1048576 + (size_t)(w0 + tr) * 1024 + v0 + tc) = st;
}

// ---------------------------------------------------------------------------
// W [64][224] fp32 -> Wb bf16 [64][232] (padded rows).  1 block.
__global__ __launch_bounds__(256) void cast_w(const float* __restrict__ W,
                                              short* __restrict__ Wb) {
    const int t  = threadIdx.x;
    const int o  = t >> 2;
    const int c0 = (t & 3) * 56;
    const float* wp = W + o * 224 + c0;
    short* d = Wb + o * 232 + c0;
#pragma unroll
    for (int i = 0; i < 14; ++i) {
        float4 w4 = *(const float4*)(wp + i * 4);
        s16x4 s;
        s[0] = f2bf(w4.x); s[1] = f2bf(w4.y); s[2] = f2bf(w4.z); s[3] = f2bf(w4.w);
        *(s16x4*)(d + i * 4) = s;
    }
}

// ---------------------------------------------------------------------------
// Small BT-GEMM (A^2 step): 128x128 tile, BK=32, m97 structure.
__global__ __launch_bounds__(256, 2) void gemm_bt(const short* __restrict__ Xb, long xz,
                                                  const short* __restrict__ Btb, long bz,
                                                  short* __restrict__ Cb, long cz,
                                                  int crow) {
    __shared__ __align__(16) short Alds[128 * 32];
    __shared__ __align__(16) short Blds[128 * 32];

    const int tid  = threadIdx.x;
    const int lane = tid & 63;
    const int wid  = tid >> 6;
    const int wm   = wid >> 1;
    const int wn   = wid & 1;
    const int m0   = blockIdx.y * 128;
    const int n0   = blockIdx.x * 128;

    const short* X  = Xb  + (size_t)blockIdx.z * xz;
    const short* Bt = Btb + (size_t)blockIdx.z * bz;
    short*       C  = Cb  + (size_t)blockIdx.z * cz;

    const short* Ag = X  + (size_t)(m0 + wid * 32 + (lane >> 2)) * 1024 + (lane & 3) * 8;
    const short* Bg = Bt + (size_t)(n0 + wid * 32 + (lane >> 2)) * 1024 + (lane & 3) * 8;
    short* la = &Alds[wid * 1024];
    short* lb = &Blds[wid * 1024];

    const int lane15 = lane & 15;
    const int lq     = lane >> 4;
    const int ar     = lane15 * 32 + lq * 8;

    f32x4 acc[4][4] = {};

    for (int k0 = 0; k0 < 1024; k0 += 32) {
        __syncthreads();
        gll16(Ag + k0, la);
        gll16(Ag + k0 + 16 * 1024, la + 512);
        gll16(Bg + k0, lb);
        gll16(Bg + k0 + 16 * 1024, lb + 512);
        __syncthreads();

        s16x8 af[4], bf[4];
#pragma unroll
        for (int i = 0; i < 4; ++i)
            af[i] = *(const s16x8*)&Alds[(wm * 64 + i * 16) * 32 + ar];
#pragma unroll
        for (int j = 0; j < 4; ++j)
            bf[j] = *(const s16x8*)&Blds[(wn * 64 + j * 16) * 32 + ar];
#pragma unroll
        for (int i = 0; i < 4; ++i)
#pragma unroll
            for (int j = 0; j < 4; ++j)
                acc[i][j] = mfma16(af[i], bf[j], acc[i][j]);
    }

#pragma unroll
    for (int i = 0; i < 4; ++i) {
        int rbase = m0 + wm * 64 + i * 16 + lq * 4;
#pragma unroll
        for (int r = 0; r < 4; ++r) {
            size_t rowoff = (size_t)(rbase + r) * crow;
#pragma unroll
            for (int j = 0; j < 4; ++j) {
                int col = n0 + wn * 64 + j * 16 + lane15;
                C[rowoff + col] = f2bf(acc[i][j][r]);
            }
        }
    }
}

// ---------------------------------------------------------------------------
// Main GEMM: 256x256 tile, BK=64, 8 waves (2Mx4N), 8-phase counted-vmcnt
// schedule with rotation-swizzled LDS (verified: 0 bank conflicts in core).
// Epilogue: acc -> LDS (Hcat chunk layout, rotated) -> coalesced 64B stores.

#define STAGE_A(d, h, kt) do {                                               \
    const short* _s = Agp + (h) * 65536 + (kt) * 64;                         \
    short* _l = lA + (((d) * 2 + (h)) << 13);                                \
    gll16(_s, _l);                                                           \
    gll16(_s + 131072, _l + 4096);                                           \
} while (0)

#define STAGE_B(d, h, kt) do {                                               \
    const short* _s = Bgp + (h) * 32768 + (kt) * 64;                         \
    short* _l = lB + (((d) * 2 + (h)) << 13);                                \
    gll16(_s, _l);                                                           \
    gll16(_s + 131072, _l + 4096);                                           \
} while (0)

#define RD_A(D, MH) do {                                                     \
    const short* _p = Als + (((D) * 2 + (MH)) << 13) + aBase;                \
    _Pragma("unroll")                                                        \
    for (int _fm = 0; _fm < 4; ++_fm) {                                      \
        af[_fm][0] = *(const s16x8*)(_p + _fm * 1024 + slot0);               \
        af[_fm][1] = *(const s16x8*)(_p + _fm * 1024 + (slot0 ^ 32));        \
    }                                                                        \
} while (0)

#define RD_B(D, NH, dst) do {                                                \
    const short* _p = Bls + (((D) * 2 + (NH)) << 13) + bBase;                \
    _Pragma("unroll")                                                        \
    for (int _fn = 0; _fn < 2; ++_fn) {                                      \
        dst[_fn][0] = *(const s16x8*)(_p + _fn * 1024 + slot0);              \
        dst[_fn][1] = *(const s16x8*)(_p + _fn * 1024 + (slot0 ^ 32));       \
    }                                                                        \
} while (0)

#define MM(MH, NH, bv) do {                                                  \
    __builtin_amdgcn_s_setprio(1);                                           \
    _Pragma("unroll")                                                        \
    for (int _fm = 0; _fm < 4; ++_fm) {                                      \
        _Pragma("unroll")                                                    \
        for (int _fn = 0; _fn < 2; ++_fn) {                                  \
            _Pragma("unroll")                                                \
            for (int _kk = 0; _kk < 2; ++_kk)                                \
                acc[(MH) * 4 + _fm][(NH) * 2 + _fn] =                        \
                    mfma16(af[_fm][_kk], bv[_fn][_kk],                       \
                           acc[(MH) * 4 + _fm][(NH) * 2 + _fn]);             \
        }                                                                    \
    }                                                                        \
    __builtin_amdgcn_s_setprio(0);                                           \
} while (0)

#define VM4 asm volatile("s_waitcnt vmcnt(4)" ::: "memory")
#define VM0 asm volatile("s_waitcnt vmcnt(0)" ::: "memory")

#define TILE(D, T, S1, S2, VMST) do {                                        \
    /* P1 (M0,N0) */                                                         \
    RD_A(D, 0); RD_B(D, 0, bv0);                                             \
    if (S1) STAGE_A(1 - (D), 1, (T) + 1);                                    \
    SB0; BARM; SB0; LGKM0; SB0;                                              \
    MM(0, 0, bv0);                                                           \
    SB0; BARM; SB0;                                                          \
    /* P2 (M0,N1) */                                                         \
    RD_B(D, 1, bv1);                                                         \
    if (S1) STAGE_B(1 - (D), 1, (T) + 1);                                    \
    SB0; BARM; SB0; LGKM0; SB0;                                              \
    MM(0, 1, bv1);                                                           \
    SB0; BARM; SB0;                                                          \
    /* P3 (M1,N1) */                                                         \
    RD_A(D, 1);                                                              \
    if (S2) STAGE_A((D), 0, (T) + 2);                                        \
    SB0; BARM; SB0; LGKM0; SB0;                                              \
    MM(1, 1, bv1);                                                           \
    SB0; BARM; SB0;                                                          \
    /* P4 (M1,N0) */                                                         \
    if (S2) STAGE_B((D), 0, (T) + 2);                                        \
    SB0; BARM; SB0;                                                          \
    MM(1, 0, bv0);                                                           \
    SB0; VMST; BARM; SB0;                                                    \
} while (0)

__global__ __launch_bounds__(512, 2) void gemm256(const short* __restrict__ X,
                                                  const short* __restrict__ Bt,
                                                  short* __restrict__ C) {
    __shared__ __align__(16) short LDSU[65536];  // 128 KiB (A/B tiles; epilogue union)
    short* const Als = LDSU;
    short* const Bls = LDSU + 32768;

    const int t    = threadIdx.x;
    const int lane = t & 63;
    const int w    = t >> 6;          // wave 0..7
    const int wm   = w >> 2;          // 0..1
    const int wn   = w & 3;           // 0..3
    const int r15  = lane & 15;
    const int q    = lane >> 4;       // 0..3
    const int m0   = blockIdx.y << 8;
    const int n0   = blockIdx.x << 8;

    // staging geometry (rotation-permuted global source, linear LDS dest)
    const int srow = t >> 3;                                  // 0..63
    const int kc8  = (((t & 7) - srow) & 7) * 8;              // rotated k-chunk
    const short* Agp = X + (size_t)(m0 + srow) * 1024 + kc8;
    const int rB0  = ((srow >> 5) << 6) | (srow & 31);
    const short* Bgp = Bt + (size_t)(n0 + rB0) * 1024 + kc8;
    short* lA = Als + t * 8;
    short* lB = Bls + t * 8;

    // fragment-read geometry (rotated slots)
    const int slot0 = ((q + r15) & 7) * 8;                    // kk=0; kk=1 -> ^32
    const int aBase = (wm * 64 + r15) * 64;                   // + fm*1024
    const int bBase = (wn * 32 + r15) * 64;                   // + fn*1024

    f32x4 acc[8][4] = {};
    s16x8 af[4][2], bv0[2][2], bv1[2][2];

    // prologue: T0 complete + T1 h0 halves
    STAGE_A(0, 0, 0); STAGE_A(0, 1, 0); STAGE_B(0, 0, 0); STAGE_B(0, 1, 0);
    STAGE_A(1, 0, 1); STAGE_B(1, 0, 1);
    VM4;
    BARM; SB0;

#pragma unroll 1
    for (int it = 0; it < 7; ++it) {
        const int T = it * 2;
        TILE(0, T,     true, true, VM4);
        TILE(1, T + 1, true, true, VM4);
    }
    TILE(0, 14, true,  false, VM0);
    TILE(1, 15, false, false, (void)0);

    // ---- epilogue: acc -> LDS (Hcat chunk layout, per-row rotation) ->
    // coalesced global stores (4 consecutive lanes = one aligned 64B segment).
    short* const E = LDSU;
#pragma unroll
    for (int fmt = 0; fmt < 8; ++fmt) {
        const int gl  = wm * 4 + (fmt >> 1);
        const int c16 = (fmt & 1) * 2 + (q >> 1);
#pragma unroll
        for (int fnt = 0; fnt < 4; ++fnt) {
            const int vl = wn * 64 + fnt * 16 + r15;
            s16x4 sv;
            sv[0] = f2bf(acc[fmt][fnt][0]);
            sv[1] = f2bf(acc[fmt][fnt][1]);
            sv[2] = f2bf(acc[fmt][fnt][2]);
            sv[3] = f2bf(acc[fmt][fnt][3]);
            *(s16x4*)&E[gl * 8192 + vl * 32 + (((c16 + vl) & 3) << 3) + ((q & 1) << 2)] = sv;
        }
    }
    __syncthreads();
    const int s_idx = n0 >> 10;
    const int vg0   = n0 & 1023;
    const int g0    = m0 >> 5;
#pragma unroll
    for (int i = 0; i < 16; ++i) {
        const int G   = i * 512 + t;
        const int row = G >> 2;          // 0..2047
        const int c16 = G & 3;
        const int gl  = row >> 8;
        const int vl  = row & 255;
        const int gg  = g0 + gl;
        const int bb  = gg / 12;
        const int ll  = gg - bb * 12;
        s16x8 val = *(const s16x8*)&E[gl * 8192 + vl * 32 + (((c16 + vl) & 3) << 3)];
        *(s16x8*)(C + ((size_t)bb * 12288 + (size_t)(vg0 + vl) * 12 + ll) * 192
                    + s_idx * 32 + c16 * 8) = val;
    }
}

// ---------------------------------------------------------------------------
// Final conv v3: out[o][R] = bias[o] + sum_k W[o][k]*Acat[R][k], 7 k-steps of 32.
// W staged via global_load_lds from pre-cast bf16 Wb (zero VGPR cost — fixes
// r4's register spill).  Hcat B-fragments direct global->VGPR (16 contiguous
// bytes per lane); x (k-step 0) via one-time LDS transpose.  One barrier.
__global__ __launch_bounds__(256, 2) void gemm_fin(const float* __restrict__ x,
                                                   const short* __restrict__ Hc,
                                                   const short* __restrict__ Wb,
                                                   const float* __restrict__ bias,
                                                   float* __restrict__ out) {
    __shared__ __align__(16) short Wl[16384];        // 32 KB; rows at stride 232
    __shared__ __align__(16) short Hl0[8192];        // 16 KB (x k-slice)

    const int t    = threadIdx.x;
    const int lane = t & 63;
    const int wv   = t >> 6;        // 0..3
    const int r15  = lane & 15;
    const int lq   = lane >> 4;     // 0..3
    const int blk  = blockIdx.x;
    const int b    = blk / 48;
    const int p0   = (blk - b * 48) * 256;
    const size_t R0 = (size_t)b * 12288 + p0;

    // ---- W -> LDS via gll (Wl mirrors Wb linearly; dest = base + lane*16)
#pragma unroll
    for (int i = 0; i < 8; ++i)
        gll16(Wb + (size_t)(i * 256 + t) * 8, Wl + (i * 256 + t) * 8);

    // ---- x loads (k-step 0 source)
    const int xc = t & 31, pc = t >> 5;
    const float* xp = x + ((size_t)b * 32 + xc) * 12288 + p0 + pc * 32;
    float4 xbuf[8];
#pragma unroll
    for (int j = 0; j < 8; ++j) xbuf[j] = *(const float4*)(xp + j * 4);

    // ---- Hcat B-fragments direct global->reg (each lane: 16 contiguous bytes)
    const short* hb = Hc + (R0 + wv * 64 + r15) * 192 + lq * 8;
    s16x8 bH[6][4];
#pragma unroll
    for (int s = 0; s < 6; ++s)
#pragma unroll
        for (int bt = 0; bt < 4; ++bt)
            bH[s][bt] = *(const s16x8*)(hb + (size_t)bt * (16 * 192) + s * 32);

    // ---- stage x k-slice into Hl0, rotated chunks (verified layout):
    // value (row,c) at row*32 + (((c>>3)+(row>>1))&3)*8 + (c&7)
    {
        const int kc = xc >> 3, ko = xc & 7;
#pragma unroll
        for (int j4 = 0; j4 < 8; ++j4) {
            float vals[4] = {xbuf[j4].x, xbuf[j4].y, xbuf[j4].z, xbuf[j4].w};
#pragma unroll
            for (int e = 0; e < 4; ++e) {
                int row = pc * 32 + j4 * 4 + e;
                Hl0[row * 32 + (((kc + (row >> 1)) & 3) << 3) + ko] = f2bf(vals[e]);
            }
        }
    }
    __syncthreads();

    f32x4 acc[4][4] = {};

    // step 0 (x) from LDS
    {
        s16x8 af[4], bfr[4];
#pragma unroll
        for (int ot = 0; ot < 4; ++ot)
            af[ot] = *(const s16x8*)&Wl[(ot * 16 + r15) * 232 + lq * 8];
#pragma unroll
        for (int bt = 0; bt < 4; ++bt) {
            int row = wv * 64 + bt * 16 + r15;
            bfr[bt] = *(const s16x8*)&Hl0[row * 32 + (((lq + (row >> 1)) & 3) << 3)];
        }
#pragma unroll
        for (int ot = 0; ot < 4; ++ot)
#pragma unroll
            for (int bt = 0; bt < 4; ++bt)
                acc[ot][bt] = mfma16(af[ot], bfr[bt], acc[ot][bt]);
    }
    // steps 1..6 (Hcat) from registers
#pragma unroll
    for (int s = 1; s <= 6; ++s) {
        s16x8 af[4];
#pragma unroll
        for (int ot = 0; ot < 4; ++ot)
            af[ot] = *(const s16x8*)&Wl[(ot * 16 + r15) * 232 + s * 32 + lq * 8];
#pragma unroll
        for (int ot = 0; ot < 4; ++ot)
#pragma unroll
            for (int bt = 0; bt < 4; ++bt)
                acc[ot][bt] = mfma16(af[ot], bH[s - 1][bt], acc[ot][bt]);
    }

    // ---- epilogue: out[(b*64+o)*12288 + p0 + col], col = wv*64+bt*16+r15
#pragma unroll
    for (int ot = 0; ot < 4; ++ot) {
#pragma unroll
        for (int r = 0; r < 4; ++r) {
            const int oo = ot * 16 + lq * 4 + r;
            const float bo = bias[oo];
            float* op = out + ((size_t)b * 64 + oo) * 12288 + p0;
#pragma unroll
            for (int bt = 0; bt < 4; ++bt)
                op[wv * 64 + bt * 16 + r15] = acc[ot][bt][r] + bo;
        }
    }
}

// ---------------------------------------------------------------------------
extern "C" void kernel_launch(void* const* d_in, const int* in_sizes, int n_in,
                              void* d_out, int out_size, void* d_ws, size_t ws_size,
                              hipStream_t stream) {
    const float* x  = (const float*)d_in[0];
    const float* a0 = (const float*)d_in[1];
    const float* a1 = (const float*)d_in[2];
    const float* a2 = (const float*)d_in[3];
    const float* W  = (const float*)d_in[4];
    const float* bs = (const float*)d_in[5];
    float* out = (float*)d_out;

    // workspace (bytes):
    //   Xg    bf16 [24576][1024]   @ 0           50,331,648
    //   Ab    bf16 [3][1024][1024] @ 50331648     6,291,456
    //   Btall bf16 [6][1024][1024] @ 56623104    12,582,912
    //   Hcat  bf16 [786432][192]   @ 69206016   301,989,888   (ends 371,195,904)
    //   Wb    bf16 [64][232]       @ 0 (overlays Xg AFTER gemm256 consumed it)
    char* ws = (char*)d_ws;
    short* Xg    = (short*)(ws);
    short* Ab    = (short*)(ws + 50331648L);
    short* Btall = (short*)(ws + 56623104L);
    short* Hcat  = (short*)(ws + 69206016L);
    short* Wbuf  = (short*)(ws);               // reuses Xg region (stream-serial)

    cast_x_v2<<<2048, 256, 0, stream>>>(x, Xg);
    cast_a_v2<<<dim3(32, 32, 3), 256, 0, stream>>>(a0, a1, a2, Btall, Ab);

    // (A_j^2)^T via small BT-GEMM -> slice 2j+1
    gemm_bt<<<dim3(8, 8, 3), 256, 0, stream>>>(
        Btall, 2097152L, Ab, 1048576L, Btall + 1048576L, 2097152L, 1024);

    // all 6 diffusion outputs: Hcat[R][s*32+c]
    gemm256<<<dim3(24, 96), 512, 0, stream>>>(Xg, Btall, Hcat);

    // W cast (writes into the now-free Xg region)
    cast_w<<<1, 256, 0, stream>>>(W, Wbuf);

    // fused 1x1 conv (x as k-step 0; Hcat fragments direct global->reg)
    gemm_fin<<<3072, 256, 0, stream>>>(x, Hcat, Wbuf, bs, out);
}

// Round 6
// 678.332 us; speedup vs baseline: 1.3596x; 1.0216x over previous
//
#include <hip/hip_runtime.h>
#include <hip/hip_bf16.h>

// B=64, C=32, V=1024, L=12, C_OUT=64, C_CAT=224
// M = B*C*L = 24576 rows; N = 6 slices * 1024 = 6144 cols; K = 1024.
// Row order m' = (b*12 + l)*32 + c  (so 32 consecutive rows = one (b,l) group).
// Slice order s: 0=A0^T, 1=(A0^2)^T, 2=A1^T, 3=(A1^2)^T, 4=A2^T, 5=(A2^2)^T
// Hcat[R][k]: R = b*12288 + v*12 + l, k = s*32 + c  (192 wide, bf16).
// Final conv: out[b,o,p] = bias[o] + sum_c W[o][c] x[b,c,p] + sum_k W[o][32+k] Hcat[R][k].

typedef __attribute__((ext_vector_type(4))) float  f32x4;
typedef __attribute__((ext_vector_type(8))) short  s16x8;
typedef __attribute__((ext_vector_type(4))) short  s16x4;

__device__ inline short f2bf(float f) {
    unsigned u = __builtin_bit_cast(unsigned, f);
    unsigned r = (u + 0x7FFFu + ((u >> 16) & 1u)) >> 16;   // RNE
    return (short)r;
}

__device__ inline f32x4 mfma16(s16x8 a, s16x8 b, f32x4 c) {
    return __builtin_amdgcn_mfma_f32_16x16x32_bf16(a, b, c, 0, 0, 0);
}

__device__ inline void gll16(const void* g, void* l) {
    __builtin_amdgcn_global_load_lds(
        (const __attribute__((address_space(1))) void*)g,
        (__attribute__((address_space(3))) void*)l, 16, 0, 0);
}

#define SB0   __builtin_amdgcn_sched_barrier(0)
#define BARM  asm volatile("s_barrier" ::: "memory")
#define LGKM0 asm volatile("s_waitcnt lgkmcnt(0)" ::: "memory")

// ---------------------------------------------------------------------------
// x [B,C,V,L] fp32 -> Xg bf16 [(b*12+l)*32 + c][v].  One block per bc slab.
__global__ __launch_bounds__(256) void cast_x_v2(const float* __restrict__ x,
                                                 short* __restrict__ Xg) {
    __shared__ short Xl[12 * 1040];
    const int bc = blockIdx.x;
    const int t  = threadIdx.x;
    const int b  = bc >> 5;
    const int c  = bc & 31;
    const float4* src = (const float4*)(x + (size_t)bc * 12288);
#pragma unroll
    for (int k = 0; k < 12; ++k) {
        int f4 = k * 256 + t;                 // 0..3071
        float4 v = src[f4];
        int f  = f4 * 4;
        int vi = f / 12;
        int li = f - vi * 12;
        float vals[4] = {v.x, v.y, v.z, v.w};
#pragma unroll
        for (int e = 0; e < 4; ++e) {
            Xl[li * 1040 + vi] = f2bf(vals[e]);
            if (++li == 12) { li = 0; ++vi; }
        }
    }
    __syncthreads();
#pragma unroll
    for (int k = 0; k < 6; ++k) {
        int ch = k * 256 + t;                 // 0..1535
        int l  = ch >> 7;
        int v8 = ch & 127;
        *(s16x8*)(Xg + (size_t)(b * 384 + l * 32 + c) * 1024 + v8 * 8) =
            *(const s16x8*)&Xl[l * 1040 + v8 * 8];
    }
}

// ---------------------------------------------------------------------------
// A_j [v][w] fp32 -> At_j bf16 [w][v] (into Bt_all slice 2j)  +  Ab_j bf16 [v][w]
__global__ __launch_bounds__(256) void cast_a_v2(const float* __restrict__ a0,
                                                 const float* __restrict__ a1,
                                                 const float* __restrict__ a2,
                                                 short* __restrict__ Btall,
                                                 short* __restrict__ Ab) {
    __shared__ float tbuf[32][33];
    const int z = blockIdx.z;
    const float* A = (z == 0) ? a0 : ((z == 1) ? a1 : a2);
    const int v0 = blockIdx.x * 32;
    const int w0 = blockIdx.y * 32;
    const int tr = threadIdx.x >> 3;
    const int tc = (threadIdx.x & 7) << 2;
    float4 val = *(const float4*)&A[(size_t)(v0 + tr) * 1024 + w0 + tc];
    s16x4 sb;
    sb[0] = f2bf(val.x); sb[1] = f2bf(val.y); sb[2] = f2bf(val.z); sb[3] = f2bf(val.w);
    *(s16x4*)(Ab + (size_t)z * 1048576 + (size_t)(v0 + tr) * 1024 + w0 + tc) = sb;
    tbuf[tr][tc + 0] = val.x; tbuf[tr][tc + 1] = val.y;
    tbuf[tr][tc + 2] = val.z; tbuf[tr][tc + 3] = val.w;
    __syncthreads();
    s16x4 st;
#pragma unroll
    for (int i = 0; i < 4; ++i) st[i] = f2bf(tbuf[tc + i][tr]);
    *(s16x4*)(Btall + (size_t)(2 * z) * 1048576 + (size_t)(w0 + tr) * 1024 + v0 + tc) = st;
}

// ---------------------------------------------------------------------------
// W [64][224] fp32 -> Wb bf16 [64][232] (padded rows).  1 block.
__global__ __launch_bounds__(256) void cast_w(const float* __restrict__ W,
                                              short* __restrict__ Wb) {
    const int t  = threadIdx.x;
    const int o  = t >> 2;
    const int c0 = (t & 3) * 56;
    const float* wp = W + o * 224 + c0;
    short* d = Wb + o * 232 + c0;
#pragma unroll
    for (int i = 0; i < 14; ++i) {
        float4 w4 = *(const float4*)(wp + i * 4);
        s16x4 s;
        s[0] = f2bf(w4.x); s[1] = f2bf(w4.y); s[2] = f2bf(w4.z); s[3] = f2bf(w4.w);
        *(s16x4*)(d + i * 4) = s;
    }
}

// ---------------------------------------------------------------------------
// Small BT-GEMM (A^2 step): 128x128 tile, BK=32, m97 structure.
__global__ __launch_bounds__(256, 2) void gemm_bt(const short* __restrict__ Xb, long xz,
                                                  const short* __restrict__ Btb, long bz,
                                                  short* __restrict__ Cb, long cz,
                                                  int crow) {
    __shared__ __align__(16) short Alds[128 * 32];
    __shared__ __align__(16) short Blds[128 * 32];

    const int tid  = threadIdx.x;
    const int lane = tid & 63;
    const int wid  = tid >> 6;
    const int wm   = wid >> 1;
    const int wn   = wid & 1;
    const int m0   = blockIdx.y * 128;
    const int n0   = blockIdx.x * 128;

    const short* X  = Xb  + (size_t)blockIdx.z * xz;
    const short* Bt = Btb + (size_t)blockIdx.z * bz;
    short*       C  = Cb  + (size_t)blockIdx.z * cz;

    const short* Ag = X  + (size_t)(m0 + wid * 32 + (lane >> 2)) * 1024 + (lane & 3) * 8;
    const short* Bg = Bt + (size_t)(n0 + wid * 32 + (lane >> 2)) * 1024 + (lane & 3) * 8;
    short* la = &Alds[wid * 1024];
    short* lb = &Blds[wid * 1024];

    const int lane15 = lane & 15;
    const int lq     = lane >> 4;
    const int ar     = lane15 * 32 + lq * 8;

    f32x4 acc[4][4] = {};

    for (int k0 = 0; k0 < 1024; k0 += 32) {
        __syncthreads();
        gll16(Ag + k0, la);
        gll16(Ag + k0 + 16 * 1024, la + 512);
        gll16(Bg + k0, lb);
        gll16(Bg + k0 + 16 * 1024, lb + 512);
        __syncthreads();

        s16x8 af[4], bf[4];
#pragma unroll
        for (int i = 0; i < 4; ++i)
            af[i] = *(const s16x8*)&Alds[(wm * 64 + i * 16) * 32 + ar];
#pragma unroll
        for (int j = 0; j < 4; ++j)
            bf[j] = *(const s16x8*)&Blds[(wn * 64 + j * 16) * 32 + ar];
#pragma unroll
        for (int i = 0; i < 4; ++i)
#pragma unroll
            for (int j = 0; j < 4; ++j)
                acc[i][j] = mfma16(af[i], bf[j], acc[i][j]);
    }

#pragma unroll
    for (int i = 0; i < 4; ++i) {
        int rbase = m0 + wm * 64 + i * 16 + lq * 4;
#pragma unroll
        for (int r = 0; r < 4; ++r) {
            size_t rowoff = (size_t)(rbase + r) * crow;
#pragma unroll
            for (int j = 0; j < 4; ++j) {
                int col = n0 + wn * 64 + j * 16 + lane15;
                C[rowoff + col] = f2bf(acc[i][j][r]);
            }
        }
    }
}

// ---------------------------------------------------------------------------
// Main GEMM: 256x256 tile, BK=64, 8 waves (2Mx4N), 8-phase counted-vmcnt
// schedule with rotation-swizzled LDS (0 bank conflicts in core).
// Round 6: B-stationary XCD swizzle (each XCD owns 3 fixed B-panels -> L2-
// resident) + non-temporal Hcat stores (protect Xg/Btall L3 residency).

#define STAGE_A(d, h, kt) do {                                               \
    const short* _s = Agp + (h) * 65536 + (kt) * 64;                         \
    short* _l = lA + (((d) * 2 + (h)) << 13);                                \
    gll16(_s, _l);                                                           \
    gll16(_s + 131072, _l + 4096);                                           \
} while (0)

#define STAGE_B(d, h, kt) do {                                               \
    const short* _s = Bgp + (h) * 32768 + (kt) * 64;                         \
    short* _l = lB + (((d) * 2 + (h)) << 13);                                \
    gll16(_s, _l);                                                           \
    gll16(_s + 131072, _l + 4096);                                           \
} while (0)

#define RD_A(D, MH) do {                                                     \
    const short* _p = Als + (((D) * 2 + (MH)) << 13) + aBase;                \
    _Pragma("unroll")                                                        \
    for (int _fm = 0; _fm < 4; ++_fm) {                                      \
        af[_fm][0] = *(const s16x8*)(_p + _fm * 1024 + slot0);               \
        af[_fm][1] = *(const s16x8*)(_p + _fm * 1024 + (slot0 ^ 32));        \
    }                                                                        \
} while (0)

#define RD_B(D, NH, dst) do {                                                \
    const short* _p = Bls + (((D) * 2 + (NH)) << 13) + bBase;                \
    _Pragma("unroll")                                                        \
    for (int _fn = 0; _fn < 2; ++_fn) {                                      \
        dst[_fn][0] = *(const s16x8*)(_p + _fn * 1024 + slot0);              \
        dst[_fn][1] = *(const s16x8*)(_p + _fn * 1024 + (slot0 ^ 32));       \
    }                                                                        \
} while (0)

#define MM(MH, NH, bv) do {                                                  \
    __builtin_amdgcn_s_setprio(1);                                           \
    _Pragma("unroll")                                                        \
    for (int _fm = 0; _fm < 4; ++_fm) {                                      \
        _Pragma("unroll")                                                    \
        for (int _fn = 0; _fn < 2; ++_fn) {                                  \
            _Pragma("unroll")                                                \
            for (int _kk = 0; _kk < 2; ++_kk)                                \
                acc[(MH) * 4 + _fm][(NH) * 2 + _fn] =                        \
                    mfma16(af[_fm][_kk], bv[_fn][_kk],                       \
                           acc[(MH) * 4 + _fm][(NH) * 2 + _fn]);             \
        }                                                                    \
    }                                                                        \
    __builtin_amdgcn_s_setprio(0);                                           \
} while (0)

#define VM4 asm volatile("s_waitcnt vmcnt(4)" ::: "memory")
#define VM0 asm volatile("s_waitcnt vmcnt(0)" ::: "memory")

#define TILE(D, T, S1, S2, VMST) do {                                        \
    /* P1 (M0,N0) */                                                         \
    RD_A(D, 0); RD_B(D, 0, bv0);                                             \
    if (S1) STAGE_A(1 - (D), 1, (T) + 1);                                    \
    SB0; BARM; SB0; LGKM0; SB0;                                              \
    MM(0, 0, bv0);                                                           \
    SB0; BARM; SB0;                                                          \
    /* P2 (M0,N1) */                                                         \
    RD_B(D, 1, bv1);                                                         \
    if (S1) STAGE_B(1 - (D), 1, (T) + 1);                                    \
    SB0; BARM; SB0; LGKM0; SB0;                                              \
    MM(0, 1, bv1);                                                           \
    SB0; BARM; SB0;                                                          \
    /* P3 (M1,N1) */                                                         \
    RD_A(D, 1);                                                              \
    if (S2) STAGE_A((D), 0, (T) + 2);                                        \
    SB0; BARM; SB0; LGKM0; SB0;                                              \
    MM(1, 1, bv1);                                                           \
    SB0; BARM; SB0;                                                          \
    /* P4 (M1,N0) */                                                         \
    if (S2) STAGE_B((D), 0, (T) + 2);                                        \
    SB0; BARM; SB0;                                                          \
    MM(1, 0, bv0);                                                           \
    SB0; VMST; BARM; SB0;                                                    \
} while (0)

__global__ __launch_bounds__(512, 2) void gemm256(const short* __restrict__ X,
                                                  const short* __restrict__ Bt,
                                                  short* __restrict__ C) {
    __shared__ __align__(16) short LDSU[65536];  // 128 KiB (A/B tiles; epilogue union)
    short* const Als = LDSU;
    short* const Bls = LDSU + 32768;

    const int t    = threadIdx.x;
    const int lane = t & 63;
    const int w    = t >> 6;          // wave 0..7
    const int wm   = w >> 2;          // 0..1
    const int wn   = w & 3;           // 0..3
    const int r15  = lane & 15;
    const int q    = lane >> 4;       // 0..3

    // B-stationary XCD swizzle: dispatch id -> (x', y') so that XCD k
    // (ids ≡ k mod 8 under round-robin) owns x' ∈ [3k, 3k+3) only.
    // Bijective: per 24-id chunk, x' = (id%8)*3 + (id/8)%3 covers 0..23 once.
    const int id = blockIdx.y * 24 + blockIdx.x;
    const int xp = (id & 7) * 3 + ((id >> 3) % 3);
    const int yp = id / 24;
    const int m0 = yp << 8;
    const int n0 = xp << 8;

    // staging geometry (rotation-permuted global source, linear LDS dest)
    const int srow = t >> 3;                                  // 0..63
    const int kc8  = (((t & 7) - srow) & 7) * 8;              // rotated k-chunk
    const short* Agp = X + (size_t)(m0 + srow) * 1024 + kc8;
    const int rB0  = ((srow >> 5) << 6) | (srow & 31);
    const short* Bgp = Bt + (size_t)(n0 + rB0) * 1024 + kc8;
    short* lA = Als + t * 8;
    short* lB = Bls + t * 8;

    // fragment-read geometry (rotated slots)
    const int slot0 = ((q + r15) & 7) * 8;                    // kk=0; kk=1 -> ^32
    const int aBase = (wm * 64 + r15) * 64;                   // + fm*1024
    const int bBase = (wn * 32 + r15) * 64;                   // + fn*1024

    f32x4 acc[8][4] = {};
    s16x8 af[4][2], bv0[2][2], bv1[2][2];

    // prologue: T0 complete + T1 h0 halves
    STAGE_A(0, 0, 0); STAGE_A(0, 1, 0); STAGE_B(0, 0, 0); STAGE_B(0, 1, 0);
    STAGE_A(1, 0, 1); STAGE_B(1, 0, 1);
    VM4;
    BARM; SB0;

#pragma unroll 1
    for (int it = 0; it < 7; ++it) {
        const int T = it * 2;
        TILE(0, T,     true, true, VM4);
        TILE(1, T + 1, true, true, VM4);
    }
    TILE(0, 14, true,  false, VM0);
    TILE(1, 15, false, false, (void)0);

    // ---- epilogue: acc -> LDS (Hcat chunk layout, per-row rotation) ->
    // coalesced non-temporal stores (64B segments; don't pollute L2/L3).
    short* const E = LDSU;
#pragma unroll
    for (int fmt = 0; fmt < 8; ++fmt) {
        const int gl  = wm * 4 + (fmt >> 1);
        const int c16 = (fmt & 1) * 2 + (q >> 1);
#pragma unroll
        for (int fnt = 0; fnt < 4; ++fnt) {
            const int vl = wn * 64 + fnt * 16 + r15;
            s16x4 sv;
            sv[0] = f2bf(acc[fmt][fnt][0]);
            sv[1] = f2bf(acc[fmt][fnt][1]);
            sv[2] = f2bf(acc[fmt][fnt][2]);
            sv[3] = f2bf(acc[fmt][fnt][3]);
            *(s16x4*)&E[gl * 8192 + vl * 32 + (((c16 + vl) & 3) << 3) + ((q & 1) << 2)] = sv;
        }
    }
    __syncthreads();
    const int s_idx = n0 >> 10;
    const int vg0   = n0 & 1023;
    const int g0    = m0 >> 5;
#pragma unroll
    for (int i = 0; i < 16; ++i) {
        const int G   = i * 512 + t;
        const int row = G >> 2;          // 0..2047
        const int c16 = G & 3;
        const int gl  = row >> 8;
        const int vl  = row & 255;
        const int gg  = g0 + gl;
        const int bb  = gg / 12;
        const int ll  = gg - bb * 12;
        s16x8 val = *(const s16x8*)&E[gl * 8192 + vl * 32 + (((c16 + vl) & 3) << 3)];
        __builtin_nontemporal_store(val,
            (s16x8*)(C + ((size_t)bb * 12288 + (size_t)(vg0 + vl) * 12 + ll) * 192
                       + s_idx * 32 + c16 * 8));
    }
}

// ---------------------------------------------------------------------------
// Final conv: out[o][R] = bias[o] + sum_k W[o][k]*Acat[R][k], 7 k-steps of 32.
// W via global_load_lds from pre-cast bf16 Wb; Hcat B-fragments direct
// global->VGPR with NON-TEMPORAL loads (read-once stream); x (k-step 0) via
// one-time LDS transpose; non-temporal out stores (write-once stream).
__global__ __launch_bounds__(256, 2) void gemm_fin(const float* __restrict__ x,
                                                   const short* __restrict__ Hc,
                                                   const short* __restrict__ Wb,
                                                   const float* __restrict__ bias,
                                                   float* __restrict__ out) {
    __shared__ __align__(16) short Wl[16384];        // 32 KB; rows at stride 232
    __shared__ __align__(16) short Hl0[8192];        // 16 KB (x k-slice)

    const int t    = threadIdx.x;
    const int lane = t & 63;
    const int wv   = t >> 6;        // 0..3
    const int r15  = lane & 15;
    const int lq   = lane >> 4;     // 0..3
    const int blk  = blockIdx.x;
    const int b    = blk / 48;
    const int p0   = (blk - b * 48) * 256;
    const size_t R0 = (size_t)b * 12288 + p0;

    // ---- W -> LDS via gll (Wl mirrors Wb linearly; dest = base + lane*16)
#pragma unroll
    for (int i = 0; i < 8; ++i)
        gll16(Wb + (size_t)(i * 256 + t) * 8, Wl + (i * 256 + t) * 8);

    // ---- x loads (k-step 0 source)
    const int xc = t & 31, pc = t >> 5;
    const float* xp = x + ((size_t)b * 32 + xc) * 12288 + p0 + pc * 32;
    float4 xbuf[8];
#pragma unroll
    for (int j = 0; j < 8; ++j) xbuf[j] = *(const float4*)(xp + j * 4);

    // ---- Hcat B-fragments direct global->reg, non-temporal (read-once)
    const short* hb = Hc + (R0 + wv * 64 + r15) * 192 + lq * 8;
    s16x8 bH[6][4];
#pragma unroll
    for (int s = 0; s < 6; ++s)
#pragma unroll
        for (int bt = 0; bt < 4; ++bt)
            bH[s][bt] = __builtin_nontemporal_load(
                (const s16x8*)(hb + (size_t)bt * (16 * 192) + s * 32));

    // ---- stage x k-slice into Hl0, rotated chunks (verified layout):
    // value (row,c) at row*32 + (((c>>3)+(row>>1))&3)*8 + (c&7)
    {
        const int kc = xc >> 3, ko = xc & 7;
#pragma unroll
        for (int j4 = 0; j4 < 8; ++j4) {
            float vals[4] = {xbuf[j4].x, xbuf[j4].y, xbuf[j4].z, xbuf[j4].w};
#pragma unroll
            for (int e = 0; e < 4; ++e) {
                int row = pc * 32 + j4 * 4 + e;
                Hl0[row * 32 + (((kc + (row >> 1)) & 3) << 3) + ko] = f2bf(vals[e]);
            }
        }
    }
    __syncthreads();

    f32x4 acc[4][4] = {};

    // step 0 (x) from LDS
    {
        s16x8 af[4], bfr[4];
#pragma unroll
        for (int ot = 0; ot < 4; ++ot)
            af[ot] = *(const s16x8*)&Wl[(ot * 16 + r15) * 232 + lq * 8];
#pragma unroll
        for (int bt = 0; bt < 4; ++bt) {
            int row = wv * 64 + bt * 16 + r15;
            bfr[bt] = *(const s16x8*)&Hl0[row * 32 + (((lq + (row >> 1)) & 3) << 3)];
        }
#pragma unroll
        for (int ot = 0; ot < 4; ++ot)
#pragma unroll
            for (int bt = 0; bt < 4; ++bt)
                acc[ot][bt] = mfma16(af[ot], bfr[bt], acc[ot][bt]);
    }
    // steps 1..6 (Hcat) from registers
#pragma unroll
    for (int s = 1; s <= 6; ++s) {
        s16x8 af[4];
#pragma unroll
        for (int ot = 0; ot < 4; ++ot)
            af[ot] = *(const s16x8*)&Wl[(ot * 16 + r15) * 232 + s * 32 + lq * 8];
#pragma unroll
        for (int ot = 0; ot < 4; ++ot)
#pragma unroll
            for (int bt = 0; bt < 4; ++bt)
                acc[ot][bt] = mfma16(af[ot], bH[s - 1][bt], acc[ot][bt]);
    }

    // ---- epilogue: non-temporal out stores
#pragma unroll
    for (int ot = 0; ot < 4; ++ot) {
#pragma unroll
        for (int r = 0; r < 4; ++r) {
            const int oo = ot * 16 + lq * 4 + r;
            const float bo = bias[oo];
            float* op = out + ((size_t)b * 64 + oo) * 12288 + p0;
#pragma unroll
            for (int bt = 0; bt < 4; ++bt)
                __builtin_nontemporal_store(acc[ot][bt][r] + bo,
                                            op + wv * 64 + bt * 16 + r15);
        }
    }
}

// ---------------------------------------------------------------------------
extern "C" void kernel_launch(void* const* d_in, const int* in_sizes, int n_in,
                              void* d_out, int out_size, void* d_ws, size_t ws_size,
                              hipStream_t stream) {
    const float* x  = (const float*)d_in[0];
    const float* a0 = (const float*)d_in[1];
    const float* a1 = (const float*)d_in[2];
    const float* a2 = (const float*)d_in[3];
    const float* W  = (const float*)d_in[4];
    const float* bs = (const float*)d_in[5];
    float* out = (float*)d_out;

    // workspace (bytes):
    //   Xg    bf16 [24576][1024]   @ 0           50,331,648
    //   Ab    bf16 [3][1024][1024] @ 50331648     6,291,456
    //   Btall bf16 [6][1024][1024] @ 56623104    12,582,912
    //   Hcat  bf16 [786432][192]   @ 69206016   301,989,888   (ends 371,195,904)
    //   Wb    bf16 [64][232]       @ 0 (overlays Xg AFTER gemm256 consumed it)
    char* ws = (char*)d_ws;
    short* Xg    = (short*)(ws);
    short* Ab    = (short*)(ws + 50331648L);
    short* Btall = (short*)(ws + 56623104L);
    short* Hcat  = (short*)(ws + 69206016L);
    short* Wbuf  = (short*)(ws);               // reuses Xg region (stream-serial)

    cast_x_v2<<<2048, 256, 0, stream>>>(x, Xg);
    cast_a_v2<<<dim3(32, 32, 3), 256, 0, stream>>>(a0, a1, a2, Btall, Ab);

    // (A_j^2)^T via small BT-GEMM -> slice 2j+1
    gemm_bt<<<dim3(8, 8, 3), 256, 0, stream>>>(
        Btall, 2097152L, Ab, 1048576L, Btall + 1048576L, 2097152L, 1024);

    // all 6 diffusion outputs: Hcat[R][s*32+c]
    gemm256<<<dim3(24, 96), 512, 0, stream>>>(Xg, Btall, Hcat);

    // W cast (writes into the now-free Xg region)
    cast_w<<<1, 256, 0, stream>>>(W, Wbuf);

    // fused 1x1 conv (x as k-step 0; Hcat fragments direct global->reg)
    gemm_fin<<<3072, 256, 0, stream>>>(x, Hcat, Wbuf, bs, out);
}